// Round 2
// baseline (557.828 us; speedup 1.0000x reference)
//
#include <hip/hip_runtime.h>
#include <hip/hip_cooperative_groups.h>
#include <hip/hip_bf16.h>

namespace cg = cooperative_groups;

#define NN   8000
#define NE   64000
#define NE2  72000   // edges + self loops
#define NH   8
#define OC   512
#define HC   4096    // NH*OC
#define KIN  128
#define NOUT 512
#define YW   1024    // NH*KIN
#define MAXDEG 64    // in-degree = 1 + Binomial(64000,1/8000); P(>63) astronomically small
#define NEG_SLOPE 0.2f

#define VSRC_NB   128
#define BEFF_BASE 128
#define CNT_BASE  160
#define PHA_NB    442

#define PB_GEMM_NB 64
#define ATT_BASE   64
#define PHB_NB     564

#define AGG_NB    (NN/4)                  // 2000
#define GEMM_NB   ((NN/64)*(NOUT/128))    // 500
#define GRID_NB   1024                    // 4 blocks/CU x 256 CUs, exact co-residency
#define SMEM_BYTES 24576

using bf16 = __hip_bfloat16;
typedef float  f32x4  __attribute__((ext_vector_type(4)));
typedef __bf16 bf16x8 __attribute__((ext_vector_type(8)));

static __device__ __forceinline__ void gld_lds16(const bf16* g, bf16* l){
    __builtin_amdgcn_global_load_lds(
        (const __attribute__((address_space(1))) unsigned int*)g,
        (__attribute__((address_space(3))) unsigned int*)l, 16, 0, 0);
}

struct Acc24 { f32x4 a[2][4]; };

// 64x128 MFMA tile, LDS double-buffered, both operands bf16 k-contiguous.
static __device__ __forceinline__ void gemm64x128(
    const bf16* __restrict__ A, int lda, const bf16* __restrict__ BT, int ldb,
    int K, bf16* sA, bf16* sB, int tid, Acc24& acc)
{
    const int lane = tid & 63;
    const int w    = tid >> 6;
    const int wm   = w >> 1, wn = w & 1;
    const int m16  = lane & 15, q = lane >> 4;
    const int rA = tid >> 2,  kA = (tid & 3) * 8;
    const int cB0 = tid, cB1 = 256 + tid;
    const int rB0 = cB0 >> 2, kB0 = (cB0 & 3) * 8;
    const int rB1 = cB1 >> 2, kB1 = (cB1 & 3) * 8;
    const size_t gA  = (size_t)rA  * lda + kA;
    const size_t gB0 = (size_t)rB0 * ldb + kB0;
    const size_t gB1 = (size_t)rB1 * ldb + kB1;

    #pragma unroll
    for (int i=0;i<2;++i)
        #pragma unroll
        for (int j=0;j<4;++j)
            #pragma unroll
            for (int r=0;r<4;++r) acc.a[i][j][r] = 0.f;

    gld_lds16(A  + gA,  sA + tid*8);
    gld_lds16(BT + gB0, sB + cB0*8);
    gld_lds16(BT + gB1, sB + cB1*8);
    __syncthreads();

    const int nIter = K / 32;
    for (int it = 0; it < nIter; ++it){
        const int cur = it & 1, nxt = cur ^ 1;
        bf16x8 af[2], bfr[4];
        #pragma unroll
        for (int i=0;i<2;++i)
            af[i]  = *(const bf16x8*)(const void*)(sA + cur*64*32 + ((wm*32 + i*16 + m16)*32 + q*8));
        #pragma unroll
        for (int j=0;j<4;++j)
            bfr[j] = *(const bf16x8*)(const void*)(sB + cur*128*32 + ((wn*64 + j*16 + m16)*32 + q*8));
        if (it + 1 < nIter){
            int ko = (it+1) * 32;
            gld_lds16(A  + gA  + ko, sA + nxt*64*32 + tid*8);
            gld_lds16(BT + gB0 + ko, sB + nxt*128*32 + cB0*8);
            gld_lds16(BT + gB1 + ko, sB + nxt*128*32 + cB1*8);
        }
        #pragma unroll
        for (int i=0;i<2;++i)
            #pragma unroll
            for (int j=0;j<4;++j)
                acc.a[i][j] = __builtin_amdgcn_mfma_f32_16x16x32_bf16(af[i], bfr[j], acc.a[i][j], 0, 0, 0);
        __syncthreads();
    }
}

// ======================= phase bodies (shared by fused + fallback) =======================

// [0,128):   W_gat->bf16 (Wg rows 0..127) + v[k][o]
// [128,160): b_eff[o] = sum_c b_gat[c]*W_lin[c][o]  (fp32, atomicAdd partials)
// [160,442): edge bucket fill: esrc[dst*64 + pos], pos = atomicAdd(cursor)
static __device__ __forceinline__ void phaseA_body(int bid, int tid,
    const float* __restrict__ b_gat, const float* __restrict__ W_gat,
    const float* __restrict__ att_src, const float* __restrict__ att_dst,
    const float* __restrict__ W_lin, const int* __restrict__ eidx,
    bf16* __restrict__ Wg, float* __restrict__ v, float* __restrict__ b_eff,
    int* __restrict__ cursors, int* __restrict__ esrc)
{
    if (bid < VSRC_NB){
        int k = bid;
        int lane = tid & 63, g = tid >> 6;
        for (int hh = g; hh < NH; hh += 4){
            const float* wp = W_gat + (size_t)k*HC + hh*OC;
            bf16*        wb = Wg    + (size_t)k*HC + hh*OC;
            const float* as = att_src + hh*OC;
            const float* ad = att_dst + hh*OC;
            float ss = 0.f, sd = 0.f;
            #pragma unroll
            for (int c0=0; c0<OC; c0+=64){
                float wv = wp[c0+lane];
                wb[c0+lane] = __float2bfloat16(wv);
                ss = fmaf(wv, as[c0+lane], ss);
                sd = fmaf(wv, ad[c0+lane], sd);
            }
            #pragma unroll
            for (int off=32; off; off>>=1){
                ss += __shfl_down(ss, off);
                sd += __shfl_down(sd, off);
            }
            if (lane == 0){
                v[k*16 + hh]     = ss;
                v[k*16 + 8 + hh] = sd;
            }
        }
    } else if (bid < CNT_BASE){
        int b = bid - BEFF_BASE;
        int o = tid * 2;
        const float* bg = b_gat + b*128;
        const float* wl = W_lin + (size_t)b*128*NOUT + o;
        float a0 = 0.f, a1 = 0.f;
        #pragma unroll 4
        for (int c=0; c<128; ++c){
            float bv = bg[c];
            float2 wv = *(const float2*)(wl + (size_t)c*NOUT);
            a0 = fmaf(bv, wv.x, a0);
            a1 = fmaf(bv, wv.y, a1);
        }
        atomicAdd(b_eff + o,     a0);
        atomicAdd(b_eff + o + 1, a1);
    } else {
        int e = (bid - CNT_BASE)*256 + tid;
        if (e < NE2){
            int src, dst;
            if (e < NE){ src = eidx[e]; dst = eidx[NE+e]; } else { src = dst = e - NE; }
            int pos = atomicAdd(&cursors[dst], 1);
            if (pos < MAXDEG) esrc[dst*MAXDEG + pos] = src;
        }
    }
}

// GEMM (64 blk): D[k'][o] = sum_c Wg[k'][h*512+c] * W_lin[h*512+c][o] -> WcT[o][h*128+k']
// attn2 (500 blk): a_src/a_dst[n][h] = x[n] . v[:,h]
static __device__ __forceinline__ void phaseB_body(int bid, int tid,
    const bf16* __restrict__ Wg, const float* __restrict__ W_lin,
    bf16* __restrict__ WcT,
    const float* __restrict__ x, const float* __restrict__ v,
    float* __restrict__ a_src, float* __restrict__ a_dst)
{
    extern __shared__ __align__(16) char smem_dyn[];
    if (bid < PB_GEMM_NB){
        bf16* sA = (bf16*)smem_dyn;              // 64*32*2B  = 4 KB
        bf16* sB = (bf16*)smem_dyn + 64*32;      // 128*32*2B = 8 KB

        const int head = bid >> 3;
        const int rem  = bid & 7;
        const int m0   = (rem >> 2) * 64;      // k'-tile: 0,64
        const int n0   = (rem & 3) * 128;      // o-tile
        const int lane = tid & 63;
        const int w = tid >> 6, wm = w >> 1, wn = w & 1;
        const int m16 = lane & 15, q = lane >> 4;

        const int rA = tid >> 2, kA = (tid & 3) * 8;
        const bf16* Abase = Wg + (size_t)(m0 + rA)*HC + head*OC + kA;

        f32x4 acc[2][4];
        #pragma unroll
        for (int i=0;i<2;++i)
            #pragma unroll
            for (int j=0;j<4;++j)
                #pragma unroll
                for (int r=0;r<4;++r) acc[i][j][r] = 0.f;

        for (int kc = 0; kc < OC; kc += 32){
            __syncthreads();   // prev iter's LDS reads complete
            gld_lds16(Abase + kc, sA + tid*8);
            #pragma unroll
            for (int u=0; u<4; ++u){
                int idx = tid*4 + u;              // 0..1023
                int r    = idx >> 5;              // c_local 0..31
                int gcol = (idx & 31) * 4;        // o_local group
                const float* src = W_lin + (size_t)(head*OC + kc + r)*NOUT + n0 + gcol;
                float4 vv = *(const float4*)src;
                sB[(gcol+0)*32 + r] = __float2bfloat16(vv.x);
                sB[(gcol+1)*32 + r] = __float2bfloat16(vv.y);
                sB[(gcol+2)*32 + r] = __float2bfloat16(vv.z);
                sB[(gcol+3)*32 + r] = __float2bfloat16(vv.w);
            }
            __syncthreads();   // staging complete (incl. vmcnt drain for gld_lds)
            bf16x8 af[2], bfr[4];
            #pragma unroll
            for (int i=0;i<2;++i)
                af[i]  = *(const bf16x8*)(const void*)(sA + ((wm*32 + i*16 + m16)*32 + q*8));
            #pragma unroll
            for (int j=0;j<4;++j)
                bfr[j] = *(const bf16x8*)(const void*)(sB + ((wn*64 + j*16 + m16)*32 + q*8));
            #pragma unroll
            for (int i=0;i<2;++i)
                #pragma unroll
                for (int j=0;j<4;++j)
                    acc[i][j] = __builtin_amdgcn_mfma_f32_16x16x32_bf16(af[i], bfr[j], acc[i][j], 0, 0, 0);
        }

        #pragma unroll
        for (int i=0;i<2;++i){
            int row_base = m0 + wm*32 + i*16 + q*4;
            #pragma unroll
            for (int j=0;j<4;++j){
                int col = n0 + wn*64 + j*16 + m16;
                ushort4 pk;
                bf16 b0 = __float2bfloat16(acc[i][j][0]);
                bf16 b1 = __float2bfloat16(acc[i][j][1]);
                bf16 b2 = __float2bfloat16(acc[i][j][2]);
                bf16 b3 = __float2bfloat16(acc[i][j][3]);
                pk.x = *(unsigned short*)&b0; pk.y = *(unsigned short*)&b1;
                pk.z = *(unsigned short*)&b2; pk.w = *(unsigned short*)&b3;
                *reinterpret_cast<ushort4*>(WcT + (size_t)col*YW + head*KIN + row_base) = pk;
            }
        }
        return;
    }

    // ---- attn2 ----
    float (*xs)[132] = (float(*)[132])smem_dyn;
    float (*vt)[132] = (float(*)[132])(smem_dyn + 16*132*4);
    int node0 = (bid - ATT_BASE) * 16;
    {
        const float* xg = x + (size_t)node0*KIN;
        int row = tid >> 4, co = (tid & 15) * 8;
        float4 v0 = *(const float4*)(xg + row*KIN + co);
        float4 v1 = *(const float4*)(xg + row*KIN + co + 4);
        *(float4*)&xs[row][co]     = v0;
        *(float4*)&xs[row][co + 4] = v1;
    }
    {
        int base = tid*8;
        #pragma unroll
        for (int j=0;j<8;++j){
            int idx = base + j;
            vt[idx & 15][idx >> 4] = v[idx];
        }
    }
    __syncthreads();
    int ln = tid >> 4, o = tid & 15;
    float acc = 0.f;
    #pragma unroll
    for (int k0=0;k0<KIN;k0+=4){
        float4 xv = *(const float4*)&xs[ln][k0];
        float4 vv = *(const float4*)&vt[o][k0];
        acc += xv.x*vv.x + xv.y*vv.y + xv.z*vv.z + xv.w*vv.w;
    }
    int node = node0 + ln;
    if (o < 8) a_src[node*NH + o]     = acc;
    else       a_dst[node*NH + o - 8] = acc;
}

static __device__ __forceinline__ void agg_body(int bid, int tid,
    const int* __restrict__ cnts, const int* __restrict__ esrc,
    const float* __restrict__ a_src, const float* __restrict__ a_dst,
    const float* __restrict__ x, bf16* __restrict__ Y)
{
    int node = bid*4 + (tid >> 6);
    int lane = tid & 63;
    int s0 = node*MAXDEG, s1 = s0 + min(cnts[node], MAXDEG);
    int g = lane >> 3, h = lane & 7;
    float adl = a_dst[node*NH + h];
    float m = -1e30f, sum = 0.f;
    for (int e = s0 + g; e < s1; e += 8){
        float l = a_src[esrc[e]*NH + h] + adl;
        l = l > 0.f ? l : NEG_SLOPE*l;
        float mn = fmaxf(m, l);
        sum = sum*__expf(m - mn) + __expf(l - mn);
        m = mn;
    }
    #pragma unroll
    for (int d=8; d<64; d<<=1){
        float mo = __shfl_xor(m, d);
        float so = __shfl_xor(sum, d);
        float mn = fmaxf(m, mo);
        sum = sum*__expf(m - mn) + so*__expf(mo - mn);
        m = mn;
    }
    float inv = 1.f / (sum + 1e-16f);
    float acc[16];
    #pragma unroll
    for (int j=0;j<16;++j) acc[j] = 0.f;
    for (int s=s0; s<s1; ++s){
        int src = esrc[s];
        float wl = 0.f;
        if (lane < 8){
            float l = a_src[src*NH + lane] + adl;
            l = l > 0.f ? l : NEG_SLOPE*l;
            wl = __expf(l - m) * inv;
        }
        float2 xv = *(const float2*)(x + (size_t)src*KIN + lane*2);
        #pragma unroll
        for (int hh=0; hh<8; ++hh){
            float wh = __shfl(wl, hh);
            acc[hh*2]   = fmaf(wh, xv.x, acc[hh*2]);
            acc[hh*2+1] = fmaf(wh, xv.y, acc[hh*2+1]);
        }
    }
    bf16* yp = Y + (size_t)node*YW + lane*2;
    #pragma unroll
    for (int hh=0; hh<8; ++hh){
        bf16 b0 = __float2bfloat16(acc[hh*2]);
        bf16 b1 = __float2bfloat16(acc[hh*2+1]);
        ushort2 pk;
        pk.x = *(unsigned short*)&b0;
        pk.y = *(unsigned short*)&b1;
        *reinterpret_cast<ushort2*>(yp + hh*KIN) = pk;
    }
}

static __device__ __forceinline__ void gemm_body(int bid, int tid,
    const bf16* __restrict__ A, const bf16* __restrict__ BT,
    const float* __restrict__ b_eff, const float* __restrict__ b_lin,
    float* __restrict__ C)
{
    extern __shared__ __align__(16) char smem_dyn[];
    bf16* sA = (bf16*)smem_dyn;
    bf16* sB = (bf16*)(smem_dyn + 8192);
    int m0 = (bid % 125) * 64;   // m fastest: 125 consecutive bids reuse the same BT tile
    int n0 = (bid / 125) * 128;
    Acc24 acc;
    gemm64x128(A + (size_t)m0*YW, YW, BT + (size_t)n0*YW, YW, YW, sA, sB, tid, acc);
    const int lane = tid & 63;
    const int w = tid >> 6, wm = w >> 1, wn = w & 1;
    const int m16 = lane & 15, q = lane >> 4;
    #pragma unroll
    for (int i=0;i<2;++i){
        int row_base = m0 + wm*32 + i*16 + q*4;
        #pragma unroll
        for (int j=0;j<4;++j){
            int col = n0 + wn*64 + j*16 + m16;
            float bval = b_eff[col] + b_lin[col];
            #pragma unroll
            for (int r=0;r<4;++r)
                C[(size_t)(row_base + r)*NOUT + col] = acc.a[i][j][r] + bval;
        }
    }
}

// ======================= fused cooperative kernel =======================
__global__ __launch_bounds__(256, 4) void k_fused(
    const float* __restrict__ x, const int* __restrict__ eidx,
    const float* __restrict__ W_gat, const float* __restrict__ b_gat,
    const float* __restrict__ att_src, const float* __restrict__ att_dst,
    const float* __restrict__ W_lin, const float* __restrict__ b_lin,
    float* __restrict__ out,
    bf16* __restrict__ Wg, bf16* __restrict__ WcT, bf16* __restrict__ Ybuf,
    float* __restrict__ v, float* __restrict__ a_src, float* __restrict__ a_dst,
    int* __restrict__ esrc, int* __restrict__ cursors, float* __restrict__ b_eff)
{
    cg::grid_group grid = cg::this_grid();
    const int tid = threadIdx.x;
    const int gbid = blockIdx.x;

    // P0: zero cursors + b_eff (replaces hipMemsetAsync)
    {
        int i = gbid*256 + tid;
        if (i < NN)   cursors[i] = 0;
        if (i < NOUT) b_eff[i]  = 0.f;
    }
    grid.sync();

    if (gbid < PHA_NB)
        phaseA_body(gbid, tid, b_gat, W_gat, att_src, att_dst, W_lin, eidx,
                    Wg, v, b_eff, cursors, esrc);
    grid.sync();

    if (gbid < PHB_NB)
        phaseB_body(gbid, tid, Wg, W_lin, WcT, x, v, a_src, a_dst);
    grid.sync();

    for (int bid = gbid; bid < AGG_NB; bid += GRID_NB)
        agg_body(bid, tid, cursors, esrc, a_src, a_dst, x, Ybuf);
    grid.sync();

    if (gbid < GEMM_NB)
        gemm_body(gbid, tid, Ybuf, WcT, b_eff, b_lin, out);
}

// ======================= standalone fallback kernels =======================
__global__ __launch_bounds__(256) void k_phaseA(
    const float* __restrict__ b_gat, const float* __restrict__ W_gat,
    const float* __restrict__ att_src, const float* __restrict__ att_dst,
    const float* __restrict__ W_lin, const int* __restrict__ eidx,
    bf16* __restrict__ Wg, float* __restrict__ v, float* __restrict__ b_eff,
    int* __restrict__ cursors, int* __restrict__ esrc)
{
    phaseA_body(blockIdx.x, threadIdx.x, b_gat, W_gat, att_src, att_dst, W_lin,
                eidx, Wg, v, b_eff, cursors, esrc);
}

__global__ __launch_bounds__(256) void k_phaseB(
    const bf16* __restrict__ Wg, const float* __restrict__ W_lin,
    bf16* __restrict__ WcT, const float* __restrict__ x,
    const float* __restrict__ v, float* __restrict__ a_src, float* __restrict__ a_dst)
{
    phaseB_body(blockIdx.x, threadIdx.x, Wg, W_lin, WcT, x, v, a_src, a_dst);
}

__global__ __launch_bounds__(256) void k_agg(const int* __restrict__ cnts,
    const int* __restrict__ esrc, const float* __restrict__ a_src,
    const float* __restrict__ a_dst, const float* __restrict__ x,
    bf16* __restrict__ Y)
{
    agg_body(blockIdx.x, threadIdx.x, cnts, esrc, a_src, a_dst, x, Y);
}

__global__ __launch_bounds__(256) void k_gemm64(
    const bf16* __restrict__ A, const bf16* __restrict__ BT,
    const float* __restrict__ b_eff, const float* __restrict__ b_lin,
    float* __restrict__ C)
{
    gemm_body(blockIdx.x, threadIdx.x, A, BT, b_eff, b_lin, C);
}

extern "C" void kernel_launch(void* const* d_in, const int* in_sizes, int n_in,
                              void* d_out, int out_size, void* d_ws, size_t ws_size,
                              hipStream_t stream)
{
    const float* x       = (const float*)d_in[0];
    const int*   eidx    = (const int*)  d_in[1];
    const float* W_gat   = (const float*)d_in[2];
    const float* b_gat   = (const float*)d_in[3];
    const float* att_src = (const float*)d_in[4];
    const float* att_dst = (const float*)d_in[5];
    const float* W_lin   = (const float*)d_in[6];
    const float* b_lin   = (const float*)d_in[7];
    float* out = (float*)d_out;

    char* p = (char*)d_ws;
    auto alloc = [&](size_t bytes){ void* r = (void*)p; p += (bytes + 255) & ~(size_t)255; return r; };
    bf16*  Wg     = (bf16*) alloc((size_t)KIN*HC*2);      // 1 MB
    bf16*  WcT    = (bf16*) alloc((size_t)NOUT*YW*2);     // 1 MB
    bf16*  Ybuf   = (bf16*) alloc((size_t)NN*YW*2);       // 16.4 MB
    float* v      = (float*)alloc((size_t)KIN*16*4);
    float* a_src  = (float*)alloc((size_t)NN*NH*4);
    float* a_dst  = (float*)alloc((size_t)NN*NH*4);
    int*   esrc   = (int*)  alloc((size_t)NN*MAXDEG*4);   // 2 MB
    int*   cursors= (int*)  alloc((size_t)NN*4);
    float* b_eff  = (float*)alloc((size_t)NOUT*4);
    if ((size_t)(p - (char*)d_ws) > ws_size) return;

    void* kargs[] = {
        (void*)&x, (void*)&eidx, (void*)&W_gat, (void*)&b_gat,
        (void*)&att_src, (void*)&att_dst, (void*)&W_lin, (void*)&b_lin,
        (void*)&out,
        (void*)&Wg, (void*)&WcT, (void*)&Ybuf,
        (void*)&v, (void*)&a_src, (void*)&a_dst,
        (void*)&esrc, (void*)&cursors, (void*)&b_eff
    };
    hipError_t err = hipLaunchCooperativeKernel(
        (const void*)k_fused, dim3(GRID_NB), dim3(256), kargs, SMEM_BYTES, stream);

    if (err != hipSuccess){
        // fallback: previous 4-launch path
        hipMemsetAsync(cursors, 0, (size_t)NN*4 + NOUT*4, stream);
        k_phaseA<<<PHA_NB, 256, 0, stream>>>(b_gat, W_gat, att_src, att_dst, W_lin,
                                             eidx, Wg, v, b_eff, cursors, esrc);
        k_phaseB<<<PHB_NB, 256, SMEM_BYTES, stream>>>(Wg, W_lin, WcT, x, v, a_src, a_dst);
        k_agg<<<AGG_NB, 256, 0, stream>>>(cursors, esrc, a_src, a_dst, x, Ybuf);
        k_gemm64<<<GEMM_NB, 256, SMEM_BYTES, stream>>>(Ybuf, WcT, b_eff, b_lin, out);
    }
}

// Round 3
// 159.510 us; speedup vs baseline: 3.4971x; 3.4971x over previous
//
#include <hip/hip_runtime.h>
#include <hip/hip_bf16.h>

#define NN   8000
#define NE   64000
#define NE2  72000   // edges + self loops
#define NH   8
#define OC   512
#define HC   4096    // NH*OC
#define KIN  128
#define NOUT 512
#define YW   1024    // NH*KIN
#define MAXDEG 64    // in-degree = 1 + Binomial(64000,1/8000); P(>63) astronomically small
#define NEG_SLOPE 0.2f

#define VSRC_NB   128
#define BEFF_BASE 128
#define CNT_BASE  160
#define PHA_NB    442

#define PB_GEMM_NB 64
#define ATT_BASE   64
#define PHB_NB     564

#define GEMM_NB   252   // 63 m-tiles x 4 n-tiles (128x128 output each)

using bf16 = __hip_bfloat16;
typedef float  f32x4  __attribute__((ext_vector_type(4)));
typedef __bf16 bf16x8 __attribute__((ext_vector_type(8)));

static __device__ __forceinline__ void gld_lds16(const bf16* g, bf16* l){
    __builtin_amdgcn_global_load_lds(
        (const __attribute__((address_space(1))) unsigned int*)g,
        (__attribute__((address_space(3))) unsigned int*)l, 16, 0, 0);
}

// ================= phase A =================
// [0,128):   W_gat->bf16 (Wg rows 0..127) + v[k][o]
// [128,160): b_eff[o] = sum_c b_gat[c]*W_lin[c][o]  (fp32, atomicAdd partials)
// [160,442): edge bucket fill: esrc[dst*64 + pos], pos = atomicAdd(cursor)
__global__ __launch_bounds__(256) void k_phaseA(
    const float* __restrict__ b_gat, const float* __restrict__ W_gat,
    const float* __restrict__ att_src, const float* __restrict__ att_dst,
    const float* __restrict__ W_lin, const int* __restrict__ eidx,
    bf16* __restrict__ Wg, float* __restrict__ v, float* __restrict__ b_eff,
    int* __restrict__ cursors, int* __restrict__ esrc)
{
    const int bid = blockIdx.x;
    const int tid = threadIdx.x;

    if (bid < VSRC_NB){
        int k = bid;
        int lane = tid & 63, g = tid >> 6;
        for (int hh = g; hh < NH; hh += 4){
            const float* wp = W_gat + (size_t)k*HC + hh*OC;
            bf16*        wb = Wg    + (size_t)k*HC + hh*OC;
            const float* as = att_src + hh*OC;
            const float* ad = att_dst + hh*OC;
            float ss = 0.f, sd = 0.f;
            #pragma unroll
            for (int c0=0; c0<OC; c0+=64){
                float wv = wp[c0+lane];
                wb[c0+lane] = __float2bfloat16(wv);
                ss = fmaf(wv, as[c0+lane], ss);
                sd = fmaf(wv, ad[c0+lane], sd);
            }
            #pragma unroll
            for (int off=32; off; off>>=1){
                ss += __shfl_down(ss, off);
                sd += __shfl_down(sd, off);
            }
            if (lane == 0){
                v[k*16 + hh]     = ss;
                v[k*16 + 8 + hh] = sd;
            }
        }
    } else if (bid < CNT_BASE){
        int b = bid - BEFF_BASE;
        int o = tid * 2;
        const float* bg = b_gat + b*128;
        const float* wl = W_lin + (size_t)b*128*NOUT + o;
        float a0 = 0.f, a1 = 0.f;
        #pragma unroll 4
        for (int c=0; c<128; ++c){
            float bv = bg[c];
            float2 wv = *(const float2*)(wl + (size_t)c*NOUT);
            a0 = fmaf(bv, wv.x, a0);
            a1 = fmaf(bv, wv.y, a1);
        }
        atomicAdd(b_eff + o,     a0);
        atomicAdd(b_eff + o + 1, a1);
    } else {
        int e = (bid - CNT_BASE)*256 + tid;
        if (e < NE2){
            int src, dst;
            if (e < NE){ src = eidx[e]; dst = eidx[NE+e]; } else { src = dst = e - NE; }
            int pos = atomicAdd(&cursors[dst], 1);
            if (pos < MAXDEG) esrc[dst*MAXDEG + pos] = src;
        }
    }
}

// ================= phase B: Wc GEMM (64 blocks) + attn2 (500 blocks) =========
__global__ __launch_bounds__(256) void k_phaseB(
    const bf16* __restrict__ Wg, const float* __restrict__ W_lin,
    bf16* __restrict__ WcT,
    const float* __restrict__ x, const float* __restrict__ v,
    float* __restrict__ a_src, float* __restrict__ a_dst)
{
    __shared__ __align__(16) char smem_raw[16*132*2*4];   // 16.9 KB, unioned
    const int bid = blockIdx.x;
    const int tid = threadIdx.x;

    if (bid < PB_GEMM_NB){
        bf16* sA = (bf16*)smem_raw;              // 64*32*2B  = 4 KB
        bf16* sB = (bf16*)smem_raw + 64*32;      // 128*32*2B = 8 KB

        const int head = bid >> 3;
        const int rem  = bid & 7;
        const int m0   = (rem >> 2) * 64;      // k'-tile: 0,64
        const int n0   = (rem & 3) * 128;      // o-tile
        const int lane = tid & 63;
        const int w = tid >> 6, wm = w >> 1, wn = w & 1;
        const int m16 = lane & 15, q = lane >> 4;

        const int rA = tid >> 2, kA = (tid & 3) * 8;
        const bf16* Abase = Wg + (size_t)(m0 + rA)*HC + head*OC + kA;

        f32x4 acc[2][4];
        #pragma unroll
        for (int i=0;i<2;++i)
            #pragma unroll
            for (int j=0;j<4;++j)
                #pragma unroll
                for (int r=0;r<4;++r) acc[i][j][r] = 0.f;

        for (int kc = 0; kc < OC; kc += 32){
            __syncthreads();   // prev iter's LDS reads complete
            gld_lds16(Abase + kc, sA + tid*8);
            #pragma unroll
            for (int u=0; u<4; ++u){
                int idx = tid*4 + u;              // 0..1023
                int r    = idx >> 5;              // c_local 0..31
                int gcol = (idx & 31) * 4;        // o_local group
                const float* src = W_lin + (size_t)(head*OC + kc + r)*NOUT + n0 + gcol;
                float4 vv = *(const float4*)src;
                sB[(gcol+0)*32 + r] = __float2bfloat16(vv.x);
                sB[(gcol+1)*32 + r] = __float2bfloat16(vv.y);
                sB[(gcol+2)*32 + r] = __float2bfloat16(vv.z);
                sB[(gcol+3)*32 + r] = __float2bfloat16(vv.w);
            }
            __syncthreads();   // staging complete (incl. vmcnt drain for gld_lds)
            bf16x8 af[2], bfr[4];
            #pragma unroll
            for (int i=0;i<2;++i)
                af[i]  = *(const bf16x8*)(const void*)(sA + ((wm*32 + i*16 + m16)*32 + q*8));
            #pragma unroll
            for (int j=0;j<4;++j)
                bfr[j] = *(const bf16x8*)(const void*)(sB + ((wn*64 + j*16 + m16)*32 + q*8));
            #pragma unroll
            for (int i=0;i<2;++i)
                #pragma unroll
                for (int j=0;j<4;++j)
                    acc[i][j] = __builtin_amdgcn_mfma_f32_16x16x32_bf16(af[i], bfr[j], acc[i][j], 0, 0, 0);
        }

        #pragma unroll
        for (int i=0;i<2;++i){
            int row_base = m0 + wm*32 + i*16 + q*4;
            #pragma unroll
            for (int j=0;j<4;++j){
                int col = n0 + wn*64 + j*16 + m16;
                ushort4 pk;
                bf16 b0 = __float2bfloat16(acc[i][j][0]);
                bf16 b1 = __float2bfloat16(acc[i][j][1]);
                bf16 b2 = __float2bfloat16(acc[i][j][2]);
                bf16 b3 = __float2bfloat16(acc[i][j][3]);
                pk.x = *(unsigned short*)&b0; pk.y = *(unsigned short*)&b1;
                pk.z = *(unsigned short*)&b2; pk.w = *(unsigned short*)&b3;
                *reinterpret_cast<ushort4*>(WcT + (size_t)col*YW + head*KIN + row_base) = pk;
            }
        }
        return;
    }

    // ---- attn2 ----
    float (*xs)[132] = (float(*)[132])smem_raw;
    float (*vt)[132] = (float(*)[132])(smem_raw + 16*132*4);
    int node0 = (bid - ATT_BASE) * 16;
    {
        const float* xg = x + (size_t)node0*KIN;
        int row = tid >> 4, co = (tid & 15) * 8;
        float4 v0 = *(const float4*)(xg + row*KIN + co);
        float4 v1 = *(const float4*)(xg + row*KIN + co + 4);
        *(float4*)&xs[row][co]     = v0;
        *(float4*)&xs[row][co + 4] = v1;
    }
    {
        int base = tid*8;
        #pragma unroll
        for (int j=0;j<8;++j){
            int idx = base + j;
            vt[idx & 15][idx >> 4] = v[idx];
        }
    }
    __syncthreads();
    int ln = tid >> 4, o = tid & 15;
    float acc = 0.f;
    #pragma unroll
    for (int k0=0;k0<KIN;k0+=4){
        float4 xv = *(const float4*)&xs[ln][k0];
        float4 vv = *(const float4*)&vt[o][k0];
        acc += xv.x*vv.x + xv.y*vv.y + xv.z*vv.z + xv.w*vv.w;
    }
    int node = node0 + ln;
    if (o < 8) a_src[node*NH + o]     = acc;
    else       a_dst[node*NH + o - 8] = acc;
}

// ================= Y aggregation (bucketed esrc) =========
__global__ __launch_bounds__(256) void k_agg(const int* __restrict__ cnts,
    const int* __restrict__ esrc, const float* __restrict__ a_src,
    const float* __restrict__ a_dst, const float* __restrict__ x,
    bf16* __restrict__ Y)
{
    int node = blockIdx.x*4 + (threadIdx.x >> 6);
    int lane = threadIdx.x & 63;
    int s0 = node*MAXDEG, s1 = s0 + min(cnts[node], MAXDEG);
    int g = lane >> 3, h = lane & 7;
    float adl = a_dst[node*NH + h];
    float m = -1e30f, sum = 0.f;
    for (int e = s0 + g; e < s1; e += 8){
        float l = a_src[esrc[e]*NH + h] + adl;
        l = l > 0.f ? l : NEG_SLOPE*l;
        float mn = fmaxf(m, l);
        sum = sum*__expf(m - mn) + __expf(l - mn);
        m = mn;
    }
    #pragma unroll
    for (int d=8; d<64; d<<=1){
        float mo = __shfl_xor(m, d);
        float so = __shfl_xor(sum, d);
        float mn = fmaxf(m, mo);
        sum = sum*__expf(m - mn) + so*__expf(mo - mn);
        m = mn;
    }
    float inv = 1.f / (sum + 1e-16f);
    float acc[16];
    #pragma unroll
    for (int j=0;j<16;++j) acc[j] = 0.f;
    for (int s=s0; s<s1; ++s){
        int src = esrc[s];
        float wl = 0.f;
        if (lane < 8){
            float l = a_src[src*NH + lane] + adl;
            l = l > 0.f ? l : NEG_SLOPE*l;
            wl = __expf(l - m) * inv;
        }
        float2 xv = *(const float2*)(x + (size_t)src*KIN + lane*2);
        #pragma unroll
        for (int hh=0; hh<8; ++hh){
            float wh = __shfl(wl, hh);
            acc[hh*2]   = fmaf(wh, xv.x, acc[hh*2]);
            acc[hh*2+1] = fmaf(wh, xv.y, acc[hh*2+1]);
        }
    }
    bf16* yp = Y + (size_t)node*YW + lane*2;
    #pragma unroll
    for (int hh=0; hh<8; ++hh){
        bf16 b0 = __float2bfloat16(acc[hh*2]);
        bf16 b1 = __float2bfloat16(acc[hh*2+1]);
        ushort2 pk;
        pk.x = *(unsigned short*)&b0;
        pk.y = *(unsigned short*)&b1;
        *reinterpret_cast<ushort2*>(yp + hh*KIN) = pk;
    }
}

// ================= final GEMM: out = Y @ WcT^T + b_eff + b_lin =================
// 128x128 tile (m97-class structure: 16 MFMA : 8 ds_read_b128 per wave-iter),
// double-buffered global_load_lds, bijective XCD swizzle (n-fastest per XCD
// chunk so the 4 n-tiles sharing an A-panel hit the same L2).
__global__ __launch_bounds__(256) void k_gemm128(
    const bf16* __restrict__ A, const bf16* __restrict__ BT,
    const float* __restrict__ b_eff, const float* __restrict__ b_lin,
    float* __restrict__ C)
{
    __shared__ __align__(16) bf16 sA[2][128*32];   // 8 KB x2
    __shared__ __align__(16) bf16 sB[2][128*32];   // 8 KB x2
    const int tid = threadIdx.x;

    // bijective XCD swizzle: nwg=252, q=31, r=4 (m204 formula)
    const int orig = blockIdx.x;
    const int xcd  = orig & 7, slot = orig >> 3;
    const int wgid = (xcd < 4 ? xcd*32 : 128 + (xcd-4)*31) + slot;
    const int m0 = (wgid >> 2) * 128;   // n-fastest: 4 consecutive wgids share A-panel
    const int n0 = (wgid & 3) * 128;

    const int lane = tid & 63;
    const int w = tid >> 6, wm = w >> 1, wn = w & 1;
    const int m16 = lane & 15, q = lane >> 4;

    // staging: 512 chunks of 8 bf16 per tile; thread covers chunk tid and tid+256
    const int c0 = tid, c1 = tid + 256;
    const int r0 = c0 >> 2, k0 = (c0 & 3) * 8;
    const int r1 = c1 >> 2, k1 = (c1 & 3) * 8;
    const size_t gA0 = (size_t)min(m0 + r0, NN-1) * YW + k0;  // clamp tail rows
    const size_t gA1 = (size_t)min(m0 + r1, NN-1) * YW + k1;
    const size_t gB0 = (size_t)(n0 + r0) * YW + k0;
    const size_t gB1 = (size_t)(n0 + r1) * YW + k1;

    f32x4 acc[4][4];
    #pragma unroll
    for (int i=0;i<4;++i)
        #pragma unroll
        for (int j=0;j<4;++j)
            #pragma unroll
            for (int r=0;r<4;++r) acc[i][j][r] = 0.f;

    gld_lds16(A  + gA0, sA[0] + c0*8);
    gld_lds16(A  + gA1, sA[0] + c1*8);
    gld_lds16(BT + gB0, sB[0] + c0*8);
    gld_lds16(BT + gB1, sB[0] + c1*8);
    __syncthreads();

    const int nIter = YW / 32;   // 32
    for (int it = 0; it < nIter; ++it){
        const int cur = it & 1, nxt = cur ^ 1;
        bf16x8 af[4], bfr[4];
        #pragma unroll
        for (int i=0;i<4;++i)
            af[i]  = *(const bf16x8*)(const void*)(sA[cur] + ((wm*64 + i*16 + m16)*32 + q*8));
        #pragma unroll
        for (int j=0;j<4;++j)
            bfr[j] = *(const bf16x8*)(const void*)(sB[cur] + ((wn*64 + j*16 + m16)*32 + q*8));
        if (it + 1 < nIter){
            const int ko = (it+1) * 32;
            gld_lds16(A  + gA0 + ko, sA[nxt] + c0*8);
            gld_lds16(A  + gA1 + ko, sA[nxt] + c1*8);
            gld_lds16(BT + gB0 + ko, sB[nxt] + c0*8);
            gld_lds16(BT + gB1 + ko, sB[nxt] + c1*8);
        }
        #pragma unroll
        for (int i=0;i<4;++i)
            #pragma unroll
            for (int j=0;j<4;++j)
                acc[i][j] = __builtin_amdgcn_mfma_f32_16x16x32_bf16(af[i], bfr[j], acc[i][j], 0, 0, 0);
        __syncthreads();
    }

    #pragma unroll
    for (int i=0;i<4;++i){
        int row_base = m0 + wm*64 + i*16 + q*4;
        #pragma unroll
        for (int j=0;j<4;++j){
            int col = n0 + wn*64 + j*16 + m16;
            float bval = b_eff[col] + b_lin[col];
            #pragma unroll
            for (int r=0;r<4;++r){
                int row = row_base + r;
                if (row < NN)
                    C[(size_t)row*NOUT + col] = acc[i][j][r] + bval;
            }
        }
    }
}

extern "C" void kernel_launch(void* const* d_in, const int* in_sizes, int n_in,
                              void* d_out, int out_size, void* d_ws, size_t ws_size,
                              hipStream_t stream)
{
    const float* x       = (const float*)d_in[0];
    const int*   eidx    = (const int*)  d_in[1];
    const float* W_gat   = (const float*)d_in[2];
    const float* b_gat   = (const float*)d_in[3];
    const float* att_src = (const float*)d_in[4];
    const float* att_dst = (const float*)d_in[5];
    const float* W_lin   = (const float*)d_in[6];
    const float* b_lin   = (const float*)d_in[7];
    float* out = (float*)d_out;

    char* p = (char*)d_ws;
    auto alloc = [&](size_t bytes){ void* r = (void*)p; p += (bytes + 255) & ~(size_t)255; return r; };
    bf16*  Wg     = (bf16*) alloc((size_t)KIN*HC*2);      // 1 MB
    bf16*  WcT    = (bf16*) alloc((size_t)NOUT*YW*2);     // 1 MB
    bf16*  Ybuf   = (bf16*) alloc((size_t)NN*YW*2);       // 16.4 MB
    float* v      = (float*)alloc((size_t)KIN*16*4);
    float* a_src  = (float*)alloc((size_t)NN*NH*4);
    float* a_dst  = (float*)alloc((size_t)NN*NH*4);
    int*   esrc   = (int*)  alloc((size_t)NN*MAXDEG*4);   // 2 MB
    // zero-init group (contiguous)
    int*   cursors= (int*)  alloc((size_t)NN*4);
    float* b_eff  = (float*)alloc((size_t)NOUT*4);
    if ((size_t)(p - (char*)d_ws) > ws_size) return;

    hipMemsetAsync(cursors, 0, (size_t)NN*4 + NOUT*4, stream);  // cursors + b_eff
    k_phaseA<<<PHA_NB, 256, 0, stream>>>(b_gat, W_gat, att_src, att_dst, W_lin,
                                         eidx, Wg, v, b_eff, cursors, esrc);
    k_phaseB<<<PHB_NB, 256, 0, stream>>>(Wg, W_lin, WcT, x, v, a_src, a_dst);
    k_agg<<<NN/4, 256, 0, stream>>>(cursors, esrc, a_src, a_dst, x, Ybuf);
    k_gemm128<<<GEMM_NB, 256, 0, stream>>>(Ybuf, WcT, b_eff, b_lin, out);
}

// Round 5
// 139.896 us; speedup vs baseline: 3.9875x; 1.1402x over previous
//
#include <hip/hip_runtime.h>
#include <hip/hip_bf16.h>

#define NN   8000
#define NE   64000
#define NE2  72000   // edges + self loops
#define NH   8
#define OC   512
#define HC   4096    // NH*OC
#define KIN  128
#define NOUT 512
#define YW   1024    // NH*KIN
#define MAXDEG 64    // in-degree = 1 + Binomial(64000,1/8000); P(>63) astronomically small
#define NEG_SLOPE 0.2f

// phase A: [0,128) W_gat->bf16 + v ;  bid==128: zero cursors
#define VSRC_NB   128
#define PHA_NB    129

// phase B: [0,64) Wc GEMM ; [64,346) edge fill ; [346,362) beff partials ; [362,862) attn2
#define PB_GEMM_NB 64
#define FILL_BASE  64
#define BEFF_BASE  346
#define ATT_BASE   362
#define PHB_NB     862

using bf16 = __hip_bfloat16;
typedef float  f32x4  __attribute__((ext_vector_type(4)));
typedef __bf16 bf16x8 __attribute__((ext_vector_type(8)));

static __device__ __forceinline__ void gld_lds16(const bf16* g, bf16* l){
    __builtin_amdgcn_global_load_lds(
        (const __attribute__((address_space(1))) unsigned int*)g,
        (__attribute__((address_space(3))) unsigned int*)l, 16, 0, 0);
}

struct Acc24 { f32x4 a[2][4]; };

// 64x128 MFMA tile, LDS double-buffered, both operands bf16 k-contiguous.
static __device__ __forceinline__ void gemm64x128(
    const bf16* __restrict__ A, int lda, const bf16* __restrict__ BT, int ldb,
    int K, bf16* sA, bf16* sB, int tid, Acc24& acc)
{
    const int lane = tid & 63;
    const int w    = tid >> 6;
    const int wm   = w >> 1, wn = w & 1;
    const int m16  = lane & 15, q = lane >> 4;
    const int rA = tid >> 2,  kA = (tid & 3) * 8;
    const int cB0 = tid, cB1 = 256 + tid;
    const int rB0 = cB0 >> 2, kB0 = (cB0 & 3) * 8;
    const int rB1 = cB1 >> 2, kB1 = (cB1 & 3) * 8;
    const size_t gA  = (size_t)rA  * lda + kA;
    const size_t gB0 = (size_t)rB0 * ldb + kB0;
    const size_t gB1 = (size_t)rB1 * ldb + kB1;

    #pragma unroll
    for (int i=0;i<2;++i)
        #pragma unroll
        for (int j=0;j<4;++j)
            #pragma unroll
            for (int r=0;r<4;++r) acc.a[i][j][r] = 0.f;

    gld_lds16(A  + gA,  sA + tid*8);
    gld_lds16(BT + gB0, sB + cB0*8);
    gld_lds16(BT + gB1, sB + cB1*8);
    __syncthreads();

    const int nIter = K / 32;
    for (int it = 0; it < nIter; ++it){
        const int cur = it & 1, nxt = cur ^ 1;
        bf16x8 af[2], bfr[4];
        #pragma unroll
        for (int i=0;i<2;++i)
            af[i]  = *(const bf16x8*)(const void*)(sA + cur*64*32 + ((wm*32 + i*16 + m16)*32 + q*8));
        #pragma unroll
        for (int j=0;j<4;++j)
            bfr[j] = *(const bf16x8*)(const void*)(sB + cur*128*32 + ((wn*64 + j*16 + m16)*32 + q*8));
        if (it + 1 < nIter){
            int ko = (it+1) * 32;
            gld_lds16(A  + gA  + ko, sA + nxt*64*32 + tid*8);
            gld_lds16(BT + gB0 + ko, sB + nxt*128*32 + cB0*8);
            gld_lds16(BT + gB1 + ko, sB + nxt*128*32 + cB1*8);
        }
        #pragma unroll
        for (int i=0;i<2;++i)
            #pragma unroll
            for (int j=0;j<4;++j)
                acc.a[i][j] = __builtin_amdgcn_mfma_f32_16x16x32_bf16(af[i], bfr[j], acc.a[i][j], 0, 0, 0);
        __syncthreads();
    }
}

// ================= phase A =================
__global__ __launch_bounds__(256) void k_phaseA(
    const float* __restrict__ W_gat,
    const float* __restrict__ att_src, const float* __restrict__ att_dst,
    bf16* __restrict__ Wg, float* __restrict__ v,
    int* __restrict__ cursors)
{
    const int bid = blockIdx.x;
    const int tid = threadIdx.x;

    if (bid < VSRC_NB){
        int k = bid;
        int lane = tid & 63, g = tid >> 6;
        for (int hh = g; hh < NH; hh += 4){
            const float* wp = W_gat + (size_t)k*HC + hh*OC;
            bf16*        wb = Wg    + (size_t)k*HC + hh*OC;
            const float* as = att_src + hh*OC;
            const float* ad = att_dst + hh*OC;
            float ss = 0.f, sd = 0.f;
            #pragma unroll
            for (int c0=0; c0<OC; c0+=64){
                float wv = wp[c0+lane];
                wb[c0+lane] = __float2bfloat16(wv);
                ss = fmaf(wv, as[c0+lane], ss);
                sd = fmaf(wv, ad[c0+lane], sd);
            }
            #pragma unroll
            for (int off=32; off; off>>=1){
                ss += __shfl_down(ss, off);
                sd += __shfl_down(sd, off);
            }
            if (lane == 0){
                v[k*16 + hh]     = ss;
                v[k*16 + 8 + hh] = sd;
            }
        }
    } else {
        // zero cursors (NN ints, NN % 4 == 0)
        for (int i = tid*4; i < NN; i += 1024){
            int4 z; z.x = z.y = z.z = z.w = 0;
            *reinterpret_cast<int4*>(cursors + i) = z;
        }
    }
}

// ================= phase B =================
// [0,64):    Wc GEMM: D[k'][o] = sum_c Wg[k'][h*512+c]*W_lin[h*512+c][o] -> WcT[o][h*128+k']
// [64,346):  edge bucket fill: esrc[dst*64+pos], pos = atomicAdd(cursor)
// [346,362): beff_part[b][o] = sum_{r in b-slice} b_gat[r]*W_lin[r][o]  (race-free)
// [362,862): attn2: a_src/a_dst[n][h] = x[n] . v[:,h]
__global__ __launch_bounds__(256) void k_phaseB(
    const bf16* __restrict__ Wg, const float* __restrict__ W_lin,
    const float* __restrict__ b_gat, const int* __restrict__ eidx,
    bf16* __restrict__ WcT, float* __restrict__ beff_part,
    int* __restrict__ cursors, int* __restrict__ esrc,
    const float* __restrict__ x, const float* __restrict__ v,
    float* __restrict__ a_src, float* __restrict__ a_dst)
{
    __shared__ __align__(16) char smem_raw[16*132*2*4];   // 16.9 KB, unioned
    const int bid = blockIdx.x;
    const int tid = threadIdx.x;

    if (bid < PB_GEMM_NB){
        bf16* sA = (bf16*)smem_raw;              // 64*32*2B  = 4 KB
        bf16* sB = (bf16*)smem_raw + 64*32;      // 128*32*2B = 8 KB

        const int head = bid >> 3;
        const int rem  = bid & 7;
        const int m0   = (rem >> 2) * 64;      // k'-tile: 0,64
        const int n0   = (rem & 3) * 128;      // o-tile
        const int lane = tid & 63;
        const int w = tid >> 6, wm = w >> 1, wn = w & 1;
        const int m16 = lane & 15, q = lane >> 4;

        const int rA = tid >> 2, kA = (tid & 3) * 8;
        const bf16* Abase = Wg + (size_t)(m0 + rA)*HC + head*OC + kA;

        f32x4 acc[2][4];
        #pragma unroll
        for (int i=0;i<2;++i)
            #pragma unroll
            for (int j=0;j<4;++j)
                #pragma unroll
                for (int r=0;r<4;++r) acc[i][j][r] = 0.f;

        for (int kc = 0; kc < OC; kc += 32){
            __syncthreads();   // prev iter's LDS reads complete
            gld_lds16(Abase + kc, sA + tid*8);
            #pragma unroll
            for (int u=0; u<4; ++u){
                int idx = tid*4 + u;              // 0..1023
                int r    = idx >> 5;              // c_local 0..31
                int gcol = (idx & 31) * 4;        // o_local group
                const float* src = W_lin + (size_t)(head*OC + kc + r)*NOUT + n0 + gcol;
                float4 vv = *(const float4*)src;
                sB[(gcol+0)*32 + r] = __float2bfloat16(vv.x);
                sB[(gcol+1)*32 + r] = __float2bfloat16(vv.y);
                sB[(gcol+2)*32 + r] = __float2bfloat16(vv.z);
                sB[(gcol+3)*32 + r] = __float2bfloat16(vv.w);
            }
            __syncthreads();   // staging complete (incl. vmcnt drain for gld_lds)
            bf16x8 af[2], bfr[4];
            #pragma unroll
            for (int i=0;i<2;++i)
                af[i]  = *(const bf16x8*)(const void*)(sA + ((wm*32 + i*16 + m16)*32 + q*8));
            #pragma unroll
            for (int j=0;j<4;++j)
                bfr[j] = *(const bf16x8*)(const void*)(sB + ((wn*64 + j*16 + m16)*32 + q*8));
            #pragma unroll
            for (int i=0;i<2;++i)
                #pragma unroll
                for (int j=0;j<4;++j)
                    acc[i][j] = __builtin_amdgcn_mfma_f32_16x16x32_bf16(af[i], bfr[j], acc[i][j], 0, 0, 0);
        }

        #pragma unroll
        for (int i=0;i<2;++i){
            int row_base = m0 + wm*32 + i*16 + q*4;
            #pragma unroll
            for (int j=0;j<4;++j){
                int col = n0 + wn*64 + j*16 + m16;
                ushort4 pk;
                bf16 b0 = __float2bfloat16(acc[i][j][0]);
                bf16 b1 = __float2bfloat16(acc[i][j][1]);
                bf16 b2 = __float2bfloat16(acc[i][j][2]);
                bf16 b3 = __float2bfloat16(acc[i][j][3]);
                pk.x = *(unsigned short*)&b0; pk.y = *(unsigned short*)&b1;
                pk.z = *(unsigned short*)&b2; pk.w = *(unsigned short*)&b3;
                *reinterpret_cast<ushort4*>(WcT + (size_t)col*YW + head*KIN + row_base) = pk;
            }
        }
        return;
    }

    if (bid < BEFF_BASE){
        // ---- edge bucket fill ----
        int e = (bid - FILL_BASE)*256 + tid;
        if (e < NE2){
            int src, dst;
            if (e < NE){ src = eidx[e]; dst = eidx[NE+e]; } else { src = dst = e - NE; }
            int pos = atomicAdd(&cursors[dst], 1);
            if (pos < MAXDEG) esrc[dst*MAXDEG + pos] = src;
        }
        return;
    }

    if (bid < ATT_BASE){
        // ---- beff partials: block b owns rows [b*256, b*256+256), all 512 cols ----
        int b = bid - BEFF_BASE;
        int o = tid * 2;
        const float* bg = b_gat + b*256;
        const float* wl = W_lin + (size_t)b*256*NOUT + o;
        float a0 = 0.f, a1 = 0.f;
        #pragma unroll 4
        for (int r=0; r<256; ++r){
            float bv = bg[r];
            float2 wv = *(const float2*)(wl + (size_t)r*NOUT);
            a0 = fmaf(bv, wv.x, a0);
            a1 = fmaf(bv, wv.y, a1);
        }
        beff_part[b*NOUT + o]     = a0;
        beff_part[b*NOUT + o + 1] = a1;
        return;
    }

    // ---- attn2 ----
    float (*xs)[132] = (float(*)[132])smem_raw;
    float (*vt)[132] = (float(*)[132])(smem_raw + 16*132*4);
    int node0 = (bid - ATT_BASE) * 16;
    {
        const float* xg = x + (size_t)node0*KIN;
        int row = tid >> 4, co = (tid & 15) * 8;
        float4 v0 = *(const float4*)(xg + row*KIN + co);
        float4 v1 = *(const float4*)(xg + row*KIN + co + 4);
        *(float4*)&xs[row][co]     = v0;
        *(float4*)&xs[row][co + 4] = v1;
    }
    {
        int base = tid*8;
        #pragma unroll
        for (int j=0;j<8;++j){
            int idx = base + j;
            vt[idx & 15][idx >> 4] = v[idx];
        }
    }
    __syncthreads();
    int ln = tid >> 4, o = tid & 15;
    float acc = 0.f;
    #pragma unroll
    for (int k0=0;k0<KIN;k0+=4){
        float4 xv = *(const float4*)&xs[ln][k0];
        float4 vv = *(const float4*)&vt[o][k0];
        acc += xv.x*vv.x + xv.y*vv.y + xv.z*vv.z + xv.w*vv.w;
    }
    int node = node0 + ln;
    if (o < 8) a_src[node*NH + o]     = acc;
    else       a_dst[node*NH + o - 8] = acc;
}

// ================= Y aggregation (bucketed esrc, 2-deep pipelined) =========
__global__ __launch_bounds__(256) void k_agg(const int* __restrict__ cnts,
    const int* __restrict__ esrc, const float* __restrict__ a_src,
    const float* __restrict__ a_dst, const float* __restrict__ x,
    bf16* __restrict__ Y)
{
    int node = blockIdx.x*4 + (threadIdx.x >> 6);
    int lane = threadIdx.x & 63;
    int s0 = node*MAXDEG, s1 = s0 + min(cnts[node], MAXDEG);
    int g = lane >> 3, h = lane & 7;
    float adl = a_dst[node*NH + h];
    float m = -1e30f, sum = 0.f;
    for (int e = s0 + g; e < s1; e += 8){
        float l = a_src[esrc[e]*NH + h] + adl;
        l = l > 0.f ? l : NEG_SLOPE*l;
        float mn = fmaxf(m, l);
        sum = sum*__expf(m - mn) + __expf(l - mn);
        m = mn;
    }
    #pragma unroll
    for (int d=8; d<64; d<<=1){
        float mo = __shfl_xor(m, d);
        float so = __shfl_xor(sum, d);
        float mn = fmaxf(m, mo);
        sum = sum*__expf(m - mn) + so*__expf(mo - mn);
        m = mn;
    }
    float inv = 1.f / (sum + 1e-16f);
    float acc[16];
    #pragma unroll
    for (int j=0;j<16;++j) acc[j] = 0.f;

    // 2-deep software pipeline: prefetch next edge's src, x row, and a_src gather
    int src_n = esrc[s0];
    float2 xv_n = *(const float2*)(x + (size_t)src_n*KIN + lane*2);
    float al_n = (lane < 8) ? a_src[src_n*NH + lane] : 0.f;
    for (int s = s0; s < s1; ++s){
        float2 xv = xv_n;
        float al = al_n;
        if (s + 1 < s1){
            int sn = esrc[s+1];
            xv_n = *(const float2*)(x + (size_t)sn*KIN + lane*2);
            al_n = (lane < 8) ? a_src[sn*NH + lane] : 0.f;
        }
        float wl = 0.f;
        if (lane < 8){
            float l = al + adl;
            l = l > 0.f ? l : NEG_SLOPE*l;
            wl = __expf(l - m) * inv;
        }
        #pragma unroll
        for (int hh=0; hh<8; ++hh){
            float wh = __shfl(wl, hh);
            acc[hh*2]   = fmaf(wh, xv.x, acc[hh*2]);
            acc[hh*2+1] = fmaf(wh, xv.y, acc[hh*2+1]);
        }
    }
    bf16* yp = Y + (size_t)node*YW + lane*2;
    #pragma unroll
    for (int hh=0; hh<8; ++hh){
        bf16 b0 = __float2bfloat16(acc[hh*2]);
        bf16 b1 = __float2bfloat16(acc[hh*2+1]);
        ushort2 pk;
        pk.x = *(unsigned short*)&b0;
        pk.y = *(unsigned short*)&b1;
        *reinterpret_cast<ushort2*>(yp + hh*KIN) = pk;
    }
}

// ================= final GEMM: out = Y @ WcT^T + sum(beff_part) + b_lin ===
__global__ __launch_bounds__(256) void k_gemm64(
    const bf16* __restrict__ A, const bf16* __restrict__ BT,
    const float* __restrict__ beff_part, const float* __restrict__ b_lin,
    float* __restrict__ C)
{
    __shared__ __align__(16) char smem_raw[24576];
    bf16* sA = (bf16*)smem_raw;
    bf16* sB = (bf16*)(smem_raw + 8192);
    const int tid = threadIdx.x;
    int m0 = blockIdx.x * 64;
    int n0 = blockIdx.y * 128;
    Acc24 acc;
    gemm64x128(A + (size_t)m0*YW, YW, BT + (size_t)n0*YW, YW, YW, sA, sB, tid, acc);
    const int lane = tid & 63;
    const int w = tid >> 6, wm = w >> 1, wn = w & 1;
    const int m16 = lane & 15, q = lane >> 4;
    #pragma unroll
    for (int j=0;j<4;++j){
        int col = n0 + wn*64 + j*16 + m16;
        float bval = b_lin[col];
        #pragma unroll
        for (int p=0;p<16;++p) bval += beff_part[p*NOUT + col];
        #pragma unroll
        for (int i=0;i<2;++i){
            int row_base = m0 + wm*32 + i*16 + q*4;
            #pragma unroll
            for (int r=0;r<4;++r)
                C[(size_t)(row_base + r)*NOUT + col] = acc.a[i][j][r] + bval;
        }
    }
}

extern "C" void kernel_launch(void* const* d_in, const int* in_sizes, int n_in,
                              void* d_out, int out_size, void* d_ws, size_t ws_size,
                              hipStream_t stream)
{
    const float* x       = (const float*)d_in[0];
    const int*   eidx    = (const int*)  d_in[1];
    const float* W_gat   = (const float*)d_in[2];
    const float* b_gat   = (const float*)d_in[3];
    const float* att_src = (const float*)d_in[4];
    const float* att_dst = (const float*)d_in[5];
    const float* W_lin   = (const float*)d_in[6];
    const float* b_lin   = (const float*)d_in[7];
    float* out = (float*)d_out;

    char* p = (char*)d_ws;
    auto alloc = [&](size_t bytes){ void* r = (void*)p; p += (bytes + 255) & ~(size_t)255; return r; };
    bf16*  Wg        = (bf16*) alloc((size_t)KIN*HC*2);      // 1 MB
    bf16*  WcT       = (bf16*) alloc((size_t)NOUT*YW*2);     // 1 MB
    bf16*  Ybuf      = (bf16*) alloc((size_t)NN*YW*2);       // 16.4 MB
    float* v         = (float*)alloc((size_t)KIN*16*4);
    float* a_src     = (float*)alloc((size_t)NN*NH*4);
    float* a_dst     = (float*)alloc((size_t)NN*NH*4);
    int*   esrc      = (int*)  alloc((size_t)NN*MAXDEG*4);   // 2 MB
    int*   cursors   = (int*)  alloc((size_t)NN*4);
    float* beff_part = (float*)alloc((size_t)16*NOUT*4);     // 32 KB
    if ((size_t)(p - (char*)d_ws) > ws_size) return;

    k_phaseA<<<PHA_NB, 256, 0, stream>>>(W_gat, att_src, att_dst, Wg, v, cursors);
    k_phaseB<<<PHB_NB, 256, 0, stream>>>(Wg, W_lin, b_gat, eidx, WcT, beff_part,
                                         cursors, esrc, x, v, a_src, a_dst);
    k_agg<<<NN/4, 256, 0, stream>>>(cursors, esrc, a_src, a_dst, x, Ybuf);
    k_gemm64<<<dim3(NN/64, NOUT/128), 256, 0, stream>>>(Ybuf, WcT, beff_part, b_lin, out);
}

// Round 6
// 136.064 us; speedup vs baseline: 4.0998x; 1.0282x over previous
//
#include <hip/hip_runtime.h>
#include <hip/hip_bf16.h>

#define NN   8000
#define NE   64000
#define NE2  72000   // edges + self loops
#define NH   8
#define OC   512
#define HC   4096    // NH*OC
#define KIN  128
#define NOUT 512
#define YW   1024    // NH*KIN
#define MAXDEG 64    // in-degree = 1 + Binomial(64000,1/8000); P(>63) astronomically small
#define NEG_SLOPE 0.2f

// phase A: [0,128) W_gat->bf16 + v ;  bid==128: zero cursors
#define VSRC_NB   128
#define PHA_NB    129

// phase B: [0,64) Wc GEMM ; [64,346) edge fill ; [346,362) beff partials ; [362,862) attn2
#define PB_GEMM_NB 64
#define FILL_BASE  64
#define BEFF_BASE  346
#define ATT_BASE   362
#define PHB_NB     862

#define GEMM_NB   500   // 125 m-tiles x 4 n-tiles (64x128 out each)

using bf16 = __hip_bfloat16;
typedef float  f32x4  __attribute__((ext_vector_type(4)));
typedef __bf16 bf16x8 __attribute__((ext_vector_type(8)));

static __device__ __forceinline__ void gld_lds16(const bf16* g, bf16* l){
    __builtin_amdgcn_global_load_lds(
        (const __attribute__((address_space(1))) unsigned int*)g,
        (__attribute__((address_space(3))) unsigned int*)l, 16, 0, 0);
}

struct Acc24 { f32x4 a[2][4]; };

// ======= 64x128 MFMA tile, BK=64, XOR-swizzled LDS (T2 both-sides), dbuf =======
// Logical A-tile [64][64] bf16, B-tile [128][64] bf16, k-contiguous rows.
// Storage: logical 16B-chunk j of row r lives at physical chunk j ^ (r&7).
// global_load_lds writes linearly (base+lane*16), so the swizzle is applied to
// the per-lane GLOBAL source address (rule 21: both-sides-or-neither).
static __device__ __forceinline__ void gemm64x128_bk64(
    const bf16* __restrict__ A, int lda, const bf16* __restrict__ BT, int ldb,
    int K, bf16* sA, bf16* sB, int tid, Acc24& acc)
{
    const int lane = tid & 63;
    const int w    = tid >> 6;
    const int wm   = w >> 1, wn = w & 1;
    const int m16  = lane & 15, q = lane >> 4;

    // A staging: 512 16B-chunks (64 rows x 8); thread covers cA0=tid, cA1=tid+256
    const int cA0 = tid,        cA1 = tid + 256;
    const int rA0 = cA0 >> 3,   jA0 = (cA0 & 7) ^ (rA0 & 7);
    const int rA1 = cA1 >> 3,   jA1 = (cA1 & 7) ^ (rA1 & 7);
    const size_t gA0 = (size_t)rA0 * lda + jA0 * 8;
    const size_t gA1 = (size_t)rA1 * lda + jA1 * 8;
    // B staging: 1024 chunks (128 rows x 8); 4 per thread
    size_t gB[4]; int cB[4];
    #pragma unroll
    for (int u=0; u<4; ++u){
        int c = tid + 256*u;
        int r = c >> 3, j = (c & 7) ^ (r & 7);
        cB[u] = c;
        gB[u] = (size_t)r * ldb + j * 8;
    }

    #pragma unroll
    for (int i=0;i<2;++i)
        #pragma unroll
        for (int j=0;j<4;++j)
            #pragma unroll
            for (int r=0;r<4;++r) acc.a[i][j][r] = 0.f;

    gld_lds16(A  + gA0, sA + cA0*8);
    gld_lds16(A  + gA1, sA + cA1*8);
    #pragma unroll
    for (int u=0; u<4; ++u) gld_lds16(BT + gB[u], sB + cB[u]*8);
    __syncthreads();

    const int nIter = K / 64;   // 16
    for (int it = 0; it < nIter; ++it){
        const int cur = it & 1, nxt = cur ^ 1;
        bf16x8 af[2][2], bfr[4][2];
        #pragma unroll
        for (int ks=0; ks<2; ++ks){
            #pragma unroll
            for (int i=0;i<2;++i){
                int row = wm*32 + i*16 + m16;
                int p   = (ks*4 + q) ^ (row & 7);
                af[i][ks] = *(const bf16x8*)(const void*)(sA + cur*64*64 + row*64 + p*8);
            }
            #pragma unroll
            for (int j=0;j<4;++j){
                int row = wn*64 + j*16 + m16;
                int p   = (ks*4 + q) ^ (row & 7);
                bfr[j][ks] = *(const bf16x8*)(const void*)(sB + cur*128*64 + row*64 + p*8);
            }
        }
        if (it + 1 < nIter){
            const size_t ko = (size_t)(it+1) * 64;
            gld_lds16(A  + gA0 + ko, sA + nxt*64*64 + cA0*8);
            gld_lds16(A  + gA1 + ko, sA + nxt*64*64 + cA1*8);
            #pragma unroll
            for (int u=0; u<4; ++u) gld_lds16(BT + gB[u] + ko, sB + nxt*128*64 + cB[u]*8);
        }
        #pragma unroll
        for (int ks=0; ks<2; ++ks)
            #pragma unroll
            for (int i=0;i<2;++i)
                #pragma unroll
                for (int j=0;j<4;++j)
                    acc.a[i][j] = __builtin_amdgcn_mfma_f32_16x16x32_bf16(af[i][ks], bfr[j][ks], acc.a[i][j], 0, 0, 0);
        __syncthreads();
    }
}

// ================= phase A =================
__global__ __launch_bounds__(256) void k_phaseA(
    const float* __restrict__ W_gat,
    const float* __restrict__ att_src, const float* __restrict__ att_dst,
    bf16* __restrict__ Wg, float* __restrict__ v,
    int* __restrict__ cursors)
{
    const int bid = blockIdx.x;
    const int tid = threadIdx.x;

    if (bid < VSRC_NB){
        int k = bid;
        int lane = tid & 63, g = tid >> 6;
        for (int hh = g; hh < NH; hh += 4){
            const float* wp = W_gat + (size_t)k*HC + hh*OC;
            bf16*        wb = Wg    + (size_t)k*HC + hh*OC;
            const float* as = att_src + hh*OC;
            const float* ad = att_dst + hh*OC;
            float ss = 0.f, sd = 0.f;
            #pragma unroll
            for (int c0=0; c0<OC; c0+=64){
                float wv = wp[c0+lane];
                wb[c0+lane] = __float2bfloat16(wv);
                ss = fmaf(wv, as[c0+lane], ss);
                sd = fmaf(wv, ad[c0+lane], sd);
            }
            #pragma unroll
            for (int off=32; off; off>>=1){
                ss += __shfl_down(ss, off);
                sd += __shfl_down(sd, off);
            }
            if (lane == 0){
                v[k*16 + hh]     = ss;
                v[k*16 + 8 + hh] = sd;
            }
        }
    } else {
        // zero cursors (NN ints, NN % 4 == 0)
        for (int i = tid*4; i < NN; i += 1024){
            int4 z; z.x = z.y = z.z = z.w = 0;
            *reinterpret_cast<int4*>(cursors + i) = z;
        }
    }
}

// ================= phase B =================
// [0,64):    Wc GEMM: D[k'][o] = sum_c Wg[k'][h*512+c]*W_lin[h*512+c][o] -> WcT[o][h*128+k']
// [64,346):  edge bucket fill: esrc[dst*64+pos], pos = atomicAdd(cursor)
// [346,362): beff_part[b][o] = sum_{r in b-slice} b_gat[r]*W_lin[r][o]  (race-free)
// [362,862): attn2: a_src/a_dst[n][h] = x[n] . v[:,h]
__global__ __launch_bounds__(256) void k_phaseB(
    const bf16* __restrict__ Wg, const float* __restrict__ W_lin,
    const float* __restrict__ b_gat, const int* __restrict__ eidx,
    bf16* __restrict__ WcT, float* __restrict__ beff_part,
    int* __restrict__ cursors, int* __restrict__ esrc,
    const float* __restrict__ x, const float* __restrict__ v,
    float* __restrict__ a_src, float* __restrict__ a_dst)
{
    __shared__ __align__(16) char smem_raw[16*132*2*4];   // 16.9 KB, unioned
    const int bid = blockIdx.x;
    const int tid = threadIdx.x;

    if (bid < PB_GEMM_NB){
        bf16* sA = (bf16*)smem_raw;              // 64*32*2B  = 4 KB
        bf16* sB = (bf16*)smem_raw + 64*32;      // 128*32*2B = 8 KB

        const int head = bid >> 3;
        const int rem  = bid & 7;
        const int m0   = (rem >> 2) * 64;      // k'-tile: 0,64
        const int n0   = (rem & 3) * 128;      // o-tile
        const int lane = tid & 63;
        const int w = tid >> 6, wm = w >> 1, wn = w & 1;
        const int m16 = lane & 15, q = lane >> 4;

        const int rA = tid >> 2, kA = (tid & 3) * 8;
        const bf16* Abase = Wg + (size_t)(m0 + rA)*HC + head*OC + kA;

        f32x4 acc[2][4];
        #pragma unroll
        for (int i=0;i<2;++i)
            #pragma unroll
            for (int j=0;j<4;++j)
                #pragma unroll
                for (int r=0;r<4;++r) acc[i][j][r] = 0.f;

        for (int kc = 0; kc < OC; kc += 32){
            __syncthreads();   // prev iter's LDS reads complete
            gld_lds16(Abase + kc, sA + tid*8);
            #pragma unroll
            for (int u=0; u<4; ++u){
                int idx = tid*4 + u;              // 0..1023
                int r    = idx >> 5;              // c_local 0..31
                int gcol = (idx & 31) * 4;        // o_local group
                const float* src = W_lin + (size_t)(head*OC + kc + r)*NOUT + n0 + gcol;
                float4 vv = *(const float4*)src;
                sB[(gcol+0)*32 + r] = __float2bfloat16(vv.x);
                sB[(gcol+1)*32 + r] = __float2bfloat16(vv.y);
                sB[(gcol+2)*32 + r] = __float2bfloat16(vv.z);
                sB[(gcol+3)*32 + r] = __float2bfloat16(vv.w);
            }
            __syncthreads();   // staging complete (incl. vmcnt drain for gld_lds)
            bf16x8 af[2], bfr[4];
            #pragma unroll
            for (int i=0;i<2;++i)
                af[i]  = *(const bf16x8*)(const void*)(sA + ((wm*32 + i*16 + m16)*32 + q*8));
            #pragma unroll
            for (int j=0;j<4;++j)
                bfr[j] = *(const bf16x8*)(const void*)(sB + ((wn*64 + j*16 + m16)*32 + q*8));
            #pragma unroll
            for (int i=0;i<2;++i)
                #pragma unroll
                for (int j=0;j<4;++j)
                    acc[i][j] = __builtin_amdgcn_mfma_f32_16x16x32_bf16(af[i], bfr[j], acc[i][j], 0, 0, 0);
        }

        #pragma unroll
        for (int i=0;i<2;++i){
            int row_base = m0 + wm*32 + i*16 + q*4;
            #pragma unroll
            for (int j=0;j<4;++j){
                int col = n0 + wn*64 + j*16 + m16;
                ushort4 pk;
                bf16 b0 = __float2bfloat16(acc[i][j][0]);
                bf16 b1 = __float2bfloat16(acc[i][j][1]);
                bf16 b2 = __float2bfloat16(acc[i][j][2]);
                bf16 b3 = __float2bfloat16(acc[i][j][3]);
                pk.x = *(unsigned short*)&b0; pk.y = *(unsigned short*)&b1;
                pk.z = *(unsigned short*)&b2; pk.w = *(unsigned short*)&b3;
                *reinterpret_cast<ushort4*>(WcT + (size_t)col*YW + head*KIN + row_base) = pk;
            }
        }
        return;
    }

    if (bid < BEFF_BASE){
        // ---- edge bucket fill ----
        int e = (bid - FILL_BASE)*256 + tid;
        if (e < NE2){
            int src, dst;
            if (e < NE){ src = eidx[e]; dst = eidx[NE+e]; } else { src = dst = e - NE; }
            int pos = atomicAdd(&cursors[dst], 1);
            if (pos < MAXDEG) esrc[dst*MAXDEG + pos] = src;
        }
        return;
    }

    if (bid < ATT_BASE){
        // ---- beff partials: block b owns rows [b*256, b*256+256), all 512 cols ----
        int b = bid - BEFF_BASE;
        int o = tid * 2;
        const float* bg = b_gat + b*256;
        const float* wl = W_lin + (size_t)b*256*NOUT + o;
        float a0 = 0.f, a1 = 0.f;
        #pragma unroll 4
        for (int r=0; r<256; ++r){
            float bv = bg[r];
            float2 wv = *(const float2*)(wl + (size_t)r*NOUT);
            a0 = fmaf(bv, wv.x, a0);
            a1 = fmaf(bv, wv.y, a1);
        }
        beff_part[b*NOUT + o]     = a0;
        beff_part[b*NOUT + o + 1] = a1;
        return;
    }

    // ---- attn2 ----
    float (*xs)[132] = (float(*)[132])smem_raw;
    float (*vt)[132] = (float(*)[132])(smem_raw + 16*132*4);
    int node0 = (bid - ATT_BASE) * 16;
    {
        const float* xg = x + (size_t)node0*KIN;
        int row = tid >> 4, co = (tid & 15) * 8;
        float4 v0 = *(const float4*)(xg + row*KIN + co);
        float4 v1 = *(const float4*)(xg + row*KIN + co + 4);
        *(float4*)&xs[row][co]     = v0;
        *(float4*)&xs[row][co + 4] = v1;
    }
    {
        int base = tid*8;
        #pragma unroll
        for (int j=0;j<8;++j){
            int idx = base + j;
            vt[idx & 15][idx >> 4] = v[idx];
        }
    }
    __syncthreads();
    int ln = tid >> 4, o = tid & 15;
    float acc = 0.f;
    #pragma unroll
    for (int k0=0;k0<KIN;k0+=4){
        float4 xv = *(const float4*)&xs[ln][k0];
        float4 vv = *(const float4*)&vt[o][k0];
        acc += xv.x*vv.x + xv.y*vv.y + xv.z*vv.z + xv.w*vv.w;
    }
    int node = node0 + ln;
    if (o < 8) a_src[node*NH + o]     = acc;
    else       a_dst[node*NH + o - 8] = acc;
}

// ================= Y aggregation (bucketed esrc, 2-deep pipelined) =========
__global__ __launch_bounds__(256) void k_agg(const int* __restrict__ cnts,
    const int* __restrict__ esrc, const float* __restrict__ a_src,
    const float* __restrict__ a_dst, const float* __restrict__ x,
    bf16* __restrict__ Y)
{
    int node = blockIdx.x*4 + (threadIdx.x >> 6);
    int lane = threadIdx.x & 63;
    int s0 = node*MAXDEG, s1 = s0 + min(cnts[node], MAXDEG);
    int g = lane >> 3, h = lane & 7;
    float adl = a_dst[node*NH + h];
    float m = -1e30f, sum = 0.f;
    for (int e = s0 + g; e < s1; e += 8){
        float l = a_src[esrc[e]*NH + h] + adl;
        l = l > 0.f ? l : NEG_SLOPE*l;
        float mn = fmaxf(m, l);
        sum = sum*__expf(m - mn) + __expf(l - mn);
        m = mn;
    }
    #pragma unroll
    for (int d=8; d<64; d<<=1){
        float mo = __shfl_xor(m, d);
        float so = __shfl_xor(sum, d);
        float mn = fmaxf(m, mo);
        sum = sum*__expf(m - mn) + so*__expf(mo - mn);
        m = mn;
    }
    float inv = 1.f / (sum + 1e-16f);
    float acc[16];
    #pragma unroll
    for (int j=0;j<16;++j) acc[j] = 0.f;

    // 2-deep software pipeline: prefetch next edge's src, x row, and a_src gather
    int src_n = esrc[s0];
    float2 xv_n = *(const float2*)(x + (size_t)src_n*KIN + lane*2);
    float al_n = (lane < 8) ? a_src[src_n*NH + lane] : 0.f;
    for (int s = s0; s < s1; ++s){
        float2 xv = xv_n;
        float al = al_n;
        if (s + 1 < s1){
            int sn = esrc[s+1];
            xv_n = *(const float2*)(x + (size_t)sn*KIN + lane*2);
            al_n = (lane < 8) ? a_src[sn*NH + lane] : 0.f;
        }
        float wl = 0.f;
        if (lane < 8){
            float l = al + adl;
            l = l > 0.f ? l : NEG_SLOPE*l;
            wl = __expf(l - m) * inv;
        }
        #pragma unroll
        for (int hh=0; hh<8; ++hh){
            float wh = __shfl(wl, hh);
            acc[hh*2]   = fmaf(wh, xv.x, acc[hh*2]);
            acc[hh*2+1] = fmaf(wh, xv.y, acc[hh*2+1]);
        }
    }
    bf16* yp = Y + (size_t)node*YW + lane*2;
    #pragma unroll
    for (int hh=0; hh<8; ++hh){
        bf16 b0 = __float2bfloat16(acc[hh*2]);
        bf16 b1 = __float2bfloat16(acc[hh*2+1]);
        ushort2 pk;
        pk.x = *(unsigned short*)&b0;
        pk.y = *(unsigned short*)&b1;
        *reinterpret_cast<ushort2*>(yp + hh*KIN) = pk;
    }
}

// ================= final GEMM: out = Y @ WcT^T + sum(beff_part) + b_lin ===
// BK=64 swizzled tile + bijective XCD swizzle (nwg=500: q=62,r=4), n-fastest
// within each XCD chunk so the 4 n-tiles sharing an A-panel hit one L2.
__global__ __launch_bounds__(256) void k_gemm64(
    const bf16* __restrict__ A, const bf16* __restrict__ BT,
    const float* __restrict__ beff_part, const float* __restrict__ b_lin,
    float* __restrict__ C)
{
    __shared__ __align__(16) bf16 sA[2*64*64];    // 16 KB
    __shared__ __align__(16) bf16 sB[2*128*64];   // 32 KB
    const int tid = threadIdx.x;

    const int orig = blockIdx.x;
    const int xcd = orig & 7, slot = orig >> 3;
    const int wgid = (xcd < 4 ? xcd*63 : 252 + (xcd-4)*62) + slot;
    const int m0 = (wgid >> 2) * 64;
    const int n0 = (wgid & 3) * 128;

    Acc24 acc;
    gemm64x128_bk64(A + (size_t)m0*YW, YW, BT + (size_t)n0*YW, YW, YW, sA, sB, tid, acc);

    const int lane = tid & 63;
    const int w = tid >> 6, wm = w >> 1, wn = w & 1;
    const int m16 = lane & 15, q = lane >> 4;
    #pragma unroll
    for (int j=0;j<4;++j){
        int col = n0 + wn*64 + j*16 + m16;
        float bval = b_lin[col];
        #pragma unroll
        for (int p=0;p<16;++p) bval += beff_part[p*NOUT + col];
        #pragma unroll
        for (int i=0;i<2;++i){
            int row_base = m0 + wm*32 + i*16 + q*4;
            #pragma unroll
            for (int r=0;r<4;++r)
                C[(size_t)(row_base + r)*NOUT + col] = acc.a[i][j][r] + bval;
        }
    }
}

extern "C" void kernel_launch(void* const* d_in, const int* in_sizes, int n_in,
                              void* d_out, int out_size, void* d_ws, size_t ws_size,
                              hipStream_t stream)
{
    const float* x       = (const float*)d_in[0];
    const int*   eidx    = (const int*)  d_in[1];
    const float* W_gat   = (const float*)d_in[2];
    const float* b_gat   = (const float*)d_in[3];
    const float* att_src = (const float*)d_in[4];
    const float* att_dst = (const float*)d_in[5];
    const float* W_lin   = (const float*)d_in[6];
    const float* b_lin   = (const float*)d_in[7];
    float* out = (float*)d_out;

    char* p = (char*)d_ws;
    auto alloc = [&](size_t bytes){ void* r = (void*)p; p += (bytes + 255) & ~(size_t)255; return r; };
    bf16*  Wg        = (bf16*) alloc((size_t)KIN*HC*2);      // 1 MB
    bf16*  WcT       = (bf16*) alloc((size_t)NOUT*YW*2);     // 1 MB
    bf16*  Ybuf      = (bf16*) alloc((size_t)NN*YW*2);       // 16.4 MB
    float* v         = (float*)alloc((size_t)KIN*16*4);
    float* a_src     = (float*)alloc((size_t)NN*NH*4);
    float* a_dst     = (float*)alloc((size_t)NN*NH*4);
    int*   esrc      = (int*)  alloc((size_t)NN*MAXDEG*4);   // 2 MB
    int*   cursors   = (int*)  alloc((size_t)NN*4);
    float* beff_part = (float*)alloc((size_t)16*NOUT*4);     // 32 KB
    if ((size_t)(p - (char*)d_ws) > ws_size) return;

    k_phaseA<<<PHA_NB, 256, 0, stream>>>(W_gat, att_src, att_dst, Wg, v, cursors);
    k_phaseB<<<PHB_NB, 256, 0, stream>>>(Wg, W_lin, b_gat, eidx, WcT, beff_part,
                                         cursors, esrc, x, v, a_src, a_dst);
    k_agg<<<NN/4, 256, 0, stream>>>(cursors, esrc, a_src, a_dst, x, Ybuf);
    k_gemm64<<<GEMM_NB, 256, 0, stream>>>(Ybuf, WcT, beff_part, b_lin, out);
}

// Round 7
// 126.951 us; speedup vs baseline: 4.3940x; 1.0718x over previous
//
#include <hip/hip_runtime.h>
#include <hip/hip_bf16.h>

#define NN   8000
#define NE   64000
#define NE2  72000   // edges + self loops
#define NH   8
#define OC   512
#define HC   4096    // NH*OC
#define KIN  128
#define NOUT 512
#define YW   1024    // NH*KIN
#define MAXDEG 64    // in-degree = 1 + Binomial(64000,1/8000); P(>63) astronomically small
#define NEG_SLOPE 0.2f

// phase A: [0,128) W_gat->bf16 + v ; 128: zero cursors ; [129,257) W_lin transpose + beff partials
#define VSRC_NB   128
#define TRN_BASE  129
#define PHA_NB    257

// phase B: [0,64) Wc GEMM ; [64,346) edge fill ; 346: beff reduce ; [347,847) attn2
#define PB_GEMM_NB 64
#define FILL_BASE  64
#define RED_BID    346
#define ATT_BASE   347
#define PHB_NB     847

#define GEMM_NB   500   // 125 m-tiles x 4 n-tiles (64x128 out each)

using bf16 = __hip_bfloat16;
typedef float  f32x4  __attribute__((ext_vector_type(4)));
typedef __bf16 bf16x8 __attribute__((ext_vector_type(8)));

static __device__ __forceinline__ void gld_lds16(const bf16* g, bf16* l){
    __builtin_amdgcn_global_load_lds(
        (const __attribute__((address_space(1))) unsigned int*)g,
        (__attribute__((address_space(3))) unsigned int*)l, 16, 0, 0);
}

struct Acc24 { f32x4 a[2][4]; };

// ======= final-GEMM tile: 64x128, BK=64, XOR-swizzled LDS (both-sides), dbuf =======
static __device__ __forceinline__ void gemm64x128_bk64(
    const bf16* __restrict__ A, int lda, const bf16* __restrict__ BT, int ldb,
    int K, bf16* sA, bf16* sB, int tid, Acc24& acc)
{
    const int lane = tid & 63;
    const int w    = tid >> 6;
    const int wm   = w >> 1, wn = w & 1;
    const int m16  = lane & 15, q = lane >> 4;

    const int cA0 = tid,        cA1 = tid + 256;
    const int rA0 = cA0 >> 3,   jA0 = (cA0 & 7) ^ (rA0 & 7);
    const int rA1 = cA1 >> 3,   jA1 = (cA1 & 7) ^ (rA1 & 7);
    const size_t gA0 = (size_t)rA0 * lda + jA0 * 8;
    const size_t gA1 = (size_t)rA1 * lda + jA1 * 8;
    size_t gB[4]; int cB[4];
    #pragma unroll
    for (int u=0; u<4; ++u){
        int c = tid + 256*u;
        int r = c >> 3, j = (c & 7) ^ (r & 7);
        cB[u] = c;
        gB[u] = (size_t)r * ldb + j * 8;
    }

    #pragma unroll
    for (int i=0;i<2;++i)
        #pragma unroll
        for (int j=0;j<4;++j)
            #pragma unroll
            for (int r=0;r<4;++r) acc.a[i][j][r] = 0.f;

    gld_lds16(A  + gA0, sA + cA0*8);
    gld_lds16(A  + gA1, sA + cA1*8);
    #pragma unroll
    for (int u=0; u<4; ++u) gld_lds16(BT + gB[u], sB + cB[u]*8);
    __syncthreads();

    const int nIter = K / 64;
    for (int it = 0; it < nIter; ++it){
        const int cur = it & 1, nxt = cur ^ 1;
        bf16x8 af[2][2], bfr[4][2];
        #pragma unroll
        for (int ks=0; ks<2; ++ks){
            #pragma unroll
            for (int i=0;i<2;++i){
                int row = wm*32 + i*16 + m16;
                int p   = (ks*4 + q) ^ (row & 7);
                af[i][ks] = *(const bf16x8*)(const void*)(sA + cur*64*64 + row*64 + p*8);
            }
            #pragma unroll
            for (int j=0;j<4;++j){
                int row = wn*64 + j*16 + m16;
                int p   = (ks*4 + q) ^ (row & 7);
                bfr[j][ks] = *(const bf16x8*)(const void*)(sB + cur*128*64 + row*64 + p*8);
            }
        }
        if (it + 1 < nIter){
            const size_t ko = (size_t)(it+1) * 64;
            gld_lds16(A  + gA0 + ko, sA + nxt*64*64 + cA0*8);
            gld_lds16(A  + gA1 + ko, sA + nxt*64*64 + cA1*8);
            #pragma unroll
            for (int u=0; u<4; ++u) gld_lds16(BT + gB[u] + ko, sB + nxt*128*64 + cB[u]*8);
        }
        #pragma unroll
        for (int ks=0; ks<2; ++ks)
            #pragma unroll
            for (int i=0;i<2;++i)
                #pragma unroll
                for (int j=0;j<4;++j)
                    acc.a[i][j] = __builtin_amdgcn_mfma_f32_16x16x32_bf16(af[i][ks], bfr[j][ks], acc.a[i][j], 0, 0, 0);
        __syncthreads();
    }
}

// ================= phase A =================
// [0,128):   W_gat->bf16 (Wg) + v[k][h]
// 128:       zero cursors
// [129,257): WlT[o][c] = bf16(W_lin[c][o]) transpose + beff_part[b][o] partials
__global__ __launch_bounds__(256) void k_phaseA(
    const float* __restrict__ W_gat,
    const float* __restrict__ att_src, const float* __restrict__ att_dst,
    const float* __restrict__ W_lin, const float* __restrict__ b_gat,
    bf16* __restrict__ Wg, float* __restrict__ v,
    bf16* __restrict__ WlT, float* __restrict__ beff_part,
    int* __restrict__ cursors)
{
    __shared__ float tl[32][132];
    __shared__ float bg_s[32];
    const int bid = blockIdx.x;
    const int tid = threadIdx.x;

    if (bid < VSRC_NB){
        int k = bid;
        int lane = tid & 63, g = tid >> 6;
        for (int hh = g; hh < NH; hh += 4){
            const float* wp = W_gat + (size_t)k*HC + hh*OC;
            bf16*        wb = Wg    + (size_t)k*HC + hh*OC;
            const float* as = att_src + hh*OC;
            const float* ad = att_dst + hh*OC;
            float ss = 0.f, sd = 0.f;
            #pragma unroll
            for (int c0=0; c0<OC; c0+=64){
                float wv = wp[c0+lane];
                wb[c0+lane] = __float2bfloat16(wv);
                ss = fmaf(wv, as[c0+lane], ss);
                sd = fmaf(wv, ad[c0+lane], sd);
            }
            #pragma unroll
            for (int off=32; off; off>>=1){
                ss += __shfl_down(ss, off);
                sd += __shfl_down(sd, off);
            }
            if (lane == 0){
                v[k*16 + hh]     = ss;
                v[k*16 + 8 + hh] = sd;
            }
        }
    } else if (bid == VSRC_NB){
        // zero cursors (NN ints, NN % 4 == 0)
        for (int i = tid*4; i < NN; i += 1024){
            int4 z; z.x = z.y = z.z = z.w = 0;
            *reinterpret_cast<int4*>(cursors + i) = z;
        }
    } else {
        // ---- W_lin transpose + beff partials: block owns c-rows [b*32, b*32+32) ----
        int b = bid - TRN_BASE;          // 0..127
        if (tid < 32) bg_s[tid] = b_gat[b*32 + tid];
        for (int sub = 0; sub < 4; ++sub){
            __syncthreads();             // prev tile use complete (also publishes bg_s)
            #pragma unroll
            for (int u = 0; u < 4; ++u){
                int f = tid + 256*u;     // 0..1023
                int row = f >> 5;        // c_local 0..31
                int cq  = f & 31;        // float4 group
                float4 vv = *(const float4*)(W_lin + (size_t)(b*32+row)*NOUT + sub*128 + cq*4);
                *(float4*)&tl[row][cq*4] = vv;
            }
            __syncthreads();
            if (tid < 128){
                float a = 0.f;
                #pragma unroll
                for (int c = 0; c < 32; ++c) a = fmaf(bg_s[c], tl[c][tid], a);
                beff_part[(size_t)b*NOUT + sub*128 + tid] = a;
            }
            {
                int o_loc = tid >> 1, half = tid & 1;
                unsigned int us[8];
                #pragma unroll
                for (int k = 0; k < 8; ++k){
                    float v0 = tl[half*16 + 2*k][o_loc];
                    float v1 = tl[half*16 + 2*k + 1][o_loc];
                    bf16 b0 = __float2bfloat16(v0), b1 = __float2bfloat16(v1);
                    us[k] = (unsigned int)*(unsigned short*)&b0
                          | ((unsigned int)*(unsigned short*)&b1 << 16);
                }
                bf16* dst = WlT + (size_t)(sub*128 + o_loc)*HC + b*32 + half*16;
                *(uint4*)(dst)     = *(uint4*)&us[0];
                *(uint4*)(dst + 8) = *(uint4*)&us[4];
            }
        }
    }
}

// ================= phase B =================
// [0,64):   Wc GEMM: D[k'][o] = sum_c Wg[k'][h*512+c]*WlT[o][h*512+c] -> WcT[o][h*128+k']
//           (pure gld_lds staging, dbuf, 2-bit XOR swizzle both sides)
// [64,346): edge bucket fill
// 346:      beff[o] = sum_b beff_part[b][o]
// [347,847): attn2
__global__ __launch_bounds__(256) void k_phaseB(
    const bf16* __restrict__ Wg, const bf16* __restrict__ WlT,
    const int* __restrict__ eidx,
    bf16* __restrict__ WcT,
    const float* __restrict__ beff_part, float* __restrict__ beff,
    int* __restrict__ cursors, int* __restrict__ esrc,
    const float* __restrict__ x, const float* __restrict__ v,
    float* __restrict__ a_src, float* __restrict__ a_dst)
{
    __shared__ __align__(16) char smem_raw[24576];
    const int bid = blockIdx.x;
    const int tid = threadIdx.x;

    if (bid < PB_GEMM_NB){
        bf16* sA = (bf16*)smem_raw;               // [2][64*32]  = 8 KB
        bf16* sB = (bf16*)smem_raw + 2*64*32;     // [2][128*32] = 16 KB

        const int head = bid >> 3;
        const int rem  = bid & 7;
        const int m0   = (rem >> 2) * 64;      // k'-tile: 0,64
        const int n0   = (rem & 3) * 128;      // o-tile
        const int lane = tid & 63;
        const int w = tid >> 6, wm = w >> 1, wn = w & 1;
        const int m16 = lane & 15, q = lane >> 4;

        // A staging: 256 chunks (64 rows x 4), source-swizzled
        const int rA = tid >> 2, jA = (tid & 3) ^ (rA & 3);
        const bf16* Asrc = Wg + (size_t)(m0 + rA)*HC + head*OC + jA*8;
        // B staging: 512 chunks (128 rows x 4), 2 per thread
        const int rB0 = tid >> 2,         jB0 = (tid & 3) ^ (rB0 & 3);
        const int rB1 = (tid + 256) >> 2, jB1 = ((tid + 256) & 3) ^ (rB1 & 3);
        const bf16* Bsrc0 = WlT + (size_t)(n0 + rB0)*HC + head*OC + jB0*8;
        const bf16* Bsrc1 = WlT + (size_t)(n0 + rB1)*HC + head*OC + jB1*8;

        f32x4 acc[2][4];
        #pragma unroll
        for (int i=0;i<2;++i)
            #pragma unroll
            for (int j=0;j<4;++j)
                #pragma unroll
                for (int r=0;r<4;++r) acc[i][j][r] = 0.f;

        gld_lds16(Asrc,  sA + tid*8);
        gld_lds16(Bsrc0, sB + tid*8);
        gld_lds16(Bsrc1, sB + (tid+256)*8);
        __syncthreads();

        const int nIter = OC / 32;   // 16
        for (int it = 0; it < nIter; ++it){
            const int cur = it & 1, nxt = cur ^ 1;
            bf16x8 af[2], bfr[4];
            #pragma unroll
            for (int i=0;i<2;++i){
                int row = wm*32 + i*16 + m16;
                int p   = q ^ (row & 3);
                af[i] = *(const bf16x8*)(const void*)(sA + cur*64*32 + row*32 + p*8);
            }
            #pragma unroll
            for (int j=0;j<4;++j){
                int row = wn*64 + j*16 + m16;
                int p   = q ^ (row & 3);
                bfr[j] = *(const bf16x8*)(const void*)(sB + cur*128*32 + row*32 + p*8);
            }
            if (it + 1 < nIter){
                int ko = (it+1) * 32;
                gld_lds16(Asrc  + ko, sA + nxt*64*32 + tid*8);
                gld_lds16(Bsrc0 + ko, sB + nxt*128*32 + tid*8);
                gld_lds16(Bsrc1 + ko, sB + nxt*128*32 + (tid+256)*8);
            }
            #pragma unroll
            for (int i=0;i<2;++i)
                #pragma unroll
                for (int j=0;j<4;++j)
                    acc[i][j] = __builtin_amdgcn_mfma_f32_16x16x32_bf16(af[i], bfr[j], acc[i][j], 0, 0, 0);
            __syncthreads();
        }

        #pragma unroll
        for (int i=0;i<2;++i){
            int row_base = m0 + wm*32 + i*16 + q*4;
            #pragma unroll
            for (int j=0;j<4;++j){
                int col = n0 + wn*64 + j*16 + m16;
                ushort4 pk;
                bf16 b0 = __float2bfloat16(acc[i][j][0]);
                bf16 b1 = __float2bfloat16(acc[i][j][1]);
                bf16 b2 = __float2bfloat16(acc[i][j][2]);
                bf16 b3 = __float2bfloat16(acc[i][j][3]);
                pk.x = *(unsigned short*)&b0; pk.y = *(unsigned short*)&b1;
                pk.z = *(unsigned short*)&b2; pk.w = *(unsigned short*)&b3;
                *reinterpret_cast<ushort4*>(WcT + (size_t)col*YW + head*KIN + row_base) = pk;
            }
        }
        return;
    }

    if (bid < RED_BID){
        // ---- edge bucket fill ----
        int e = (bid - FILL_BASE)*256 + tid;
        if (e < NE2){
            int src, dst;
            if (e < NE){ src = eidx[e]; dst = eidx[NE+e]; } else { src = dst = e - NE; }
            int pos = atomicAdd(&cursors[dst], 1);
            if (pos < MAXDEG) esrc[dst*MAXDEG + pos] = src;
        }
        return;
    }

    if (bid == RED_BID){
        // ---- beff reduce: 256 threads x 2 cols ----
        int o = tid * 2;
        float s0 = 0.f, s1 = 0.f;
        for (int b = 0; b < 128; ++b){
            float2 vv = *(const float2*)(beff_part + (size_t)b*NOUT + o);
            s0 += vv.x; s1 += vv.y;
        }
        beff[o] = s0; beff[o+1] = s1;
        return;
    }

    // ---- attn2 ----
    float (*xs)[132] = (float(*)[132])smem_raw;
    float (*vt)[132] = (float(*)[132])(smem_raw + 16*132*4);
    int node0 = (bid - ATT_BASE) * 16;
    {
        const float* xg = x + (size_t)node0*KIN;
        int row = tid >> 4, co = (tid & 15) * 8;
        float4 v0 = *(const float4*)(xg + row*KIN + co);
        float4 v1 = *(const float4*)(xg + row*KIN + co + 4);
        *(float4*)&xs[row][co]     = v0;
        *(float4*)&xs[row][co + 4] = v1;
    }
    {
        int base = tid*8;
        #pragma unroll
        for (int j=0;j<8;++j){
            int idx = base + j;
            vt[idx & 15][idx >> 4] = v[idx];
        }
    }
    __syncthreads();
    int ln = tid >> 4, o = tid & 15;
    float acc = 0.f;
    #pragma unroll
    for (int k0=0;k0<KIN;k0+=4){
        float4 xv = *(const float4*)&xs[ln][k0];
        float4 vv = *(const float4*)&vt[o][k0];
        acc += xv.x*vv.x + xv.y*vv.y + xv.z*vv.z + xv.w*vv.w;
    }
    int node = node0 + ln;
    if (o < 8) a_src[node*NH + o]     = acc;
    else       a_dst[node*NH + o - 8] = acc;
}

// ================= Y aggregation (bucketed esrc, 2-deep pipelined) =========
__global__ __launch_bounds__(256) void k_agg(const int* __restrict__ cnts,
    const int* __restrict__ esrc, const float* __restrict__ a_src,
    const float* __restrict__ a_dst, const float* __restrict__ x,
    bf16* __restrict__ Y)
{
    int node = blockIdx.x*4 + (threadIdx.x >> 6);
    int lane = threadIdx.x & 63;
    int s0 = node*MAXDEG, s1 = s0 + min(cnts[node], MAXDEG);
    int g = lane >> 3, h = lane & 7;
    float adl = a_dst[node*NH + h];
    float m = -1e30f, sum = 0.f;
    for (int e = s0 + g; e < s1; e += 8){
        float l = a_src[esrc[e]*NH + h] + adl;
        l = l > 0.f ? l : NEG_SLOPE*l;
        float mn = fmaxf(m, l);
        sum = sum*__expf(m - mn) + __expf(l - mn);
        m = mn;
    }
    #pragma unroll
    for (int d=8; d<64; d<<=1){
        float mo = __shfl_xor(m, d);
        float so = __shfl_xor(sum, d);
        float mn = fmaxf(m, mo);
        sum = sum*__expf(m - mn) + so*__expf(mo - mn);
        m = mn;
    }
    float inv = 1.f / (sum + 1e-16f);
    float acc[16];
    #pragma unroll
    for (int j=0;j<16;++j) acc[j] = 0.f;

    int src_n = esrc[s0];
    float2 xv_n = *(const float2*)(x + (size_t)src_n*KIN + lane*2);
    float al_n = (lane < 8) ? a_src[src_n*NH + lane] : 0.f;
    for (int s = s0; s < s1; ++s){
        float2 xv = xv_n;
        float al = al_n;
        if (s + 1 < s1){
            int sn = esrc[s+1];
            xv_n = *(const float2*)(x + (size_t)sn*KIN + lane*2);
            al_n = (lane < 8) ? a_src[sn*NH + lane] : 0.f;
        }
        float wl = 0.f;
        if (lane < 8){
            float l = al + adl;
            l = l > 0.f ? l : NEG_SLOPE*l;
            wl = __expf(l - m) * inv;
        }
        #pragma unroll
        for (int hh=0; hh<8; ++hh){
            float wh = __shfl(wl, hh);
            acc[hh*2]   = fmaf(wh, xv.x, acc[hh*2]);
            acc[hh*2+1] = fmaf(wh, xv.y, acc[hh*2+1]);
        }
    }
    bf16* yp = Y + (size_t)node*YW + lane*2;
    #pragma unroll
    for (int hh=0; hh<8; ++hh){
        bf16 b0 = __float2bfloat16(acc[hh*2]);
        bf16 b1 = __float2bfloat16(acc[hh*2+1]);
        ushort2 pk;
        pk.x = *(unsigned short*)&b0;
        pk.y = *(unsigned short*)&b1;
        *reinterpret_cast<ushort2*>(yp + hh*KIN) = pk;
    }
}

// ================= final GEMM: out = Y @ WcT^T + beff + b_lin ===
__global__ __launch_bounds__(256) void k_gemm64(
    const bf16* __restrict__ A, const bf16* __restrict__ BT,
    const float* __restrict__ beff, const float* __restrict__ b_lin,
    float* __restrict__ C)
{
    __shared__ __align__(16) bf16 sA[2*64*64];    // 16 KB
    __shared__ __align__(16) bf16 sB[2*128*64];   // 32 KB
    const int tid = threadIdx.x;

    const int orig = blockIdx.x;
    const int xcd = orig & 7, slot = orig >> 3;
    const int wgid = (xcd < 4 ? xcd*63 : 252 + (xcd-4)*62) + slot;
    const int m0 = (wgid >> 2) * 64;
    const int n0 = (wgid & 3) * 128;

    Acc24 acc;
    gemm64x128_bk64(A + (size_t)m0*YW, YW, BT + (size_t)n0*YW, YW, YW, sA, sB, tid, acc);

    const int lane = tid & 63;
    const int w = tid >> 6, wm = w >> 1, wn = w & 1;
    const int m16 = lane & 15, q = lane >> 4;
    #pragma unroll
    for (int j=0;j<4;++j){
        int col = n0 + wn*64 + j*16 + m16;
        float bval = beff[col] + b_lin[col];
        #pragma unroll
        for (int i=0;i<2;++i){
            int row_base = m0 + wm*32 + i*16 + q*4;
            #pragma unroll
            for (int r=0;r<4;++r)
                C[(size_t)(row_base + r)*NOUT + col] = acc.a[i][j][r] + bval;
        }
    }
}

extern "C" void kernel_launch(void* const* d_in, const int* in_sizes, int n_in,
                              void* d_out, int out_size, void* d_ws, size_t ws_size,
                              hipStream_t stream)
{
    const float* x       = (const float*)d_in[0];
    const int*   eidx    = (const int*)  d_in[1];
    const float* W_gat   = (const float*)d_in[2];
    const float* b_gat   = (const float*)d_in[3];
    const float* att_src = (const float*)d_in[4];
    const float* att_dst = (const float*)d_in[5];
    const float* W_lin   = (const float*)d_in[6];
    const float* b_lin   = (const float*)d_in[7];
    float* out = (float*)d_out;

    char* p = (char*)d_ws;
    auto alloc = [&](size_t bytes){ void* r = (void*)p; p += (bytes + 255) & ~(size_t)255; return r; };
    bf16*  Wg        = (bf16*) alloc((size_t)KIN*HC*2);      // 1 MB
    bf16*  WlT       = (bf16*) alloc((size_t)NOUT*HC*2);     // 4 MB
    bf16*  WcT       = (bf16*) alloc((size_t)NOUT*YW*2);     // 1 MB
    bf16*  Ybuf      = (bf16*) alloc((size_t)NN*YW*2);       // 16.4 MB
    float* v         = (float*)alloc((size_t)KIN*16*4);
    float* a_src     = (float*)alloc((size_t)NN*NH*4);
    float* a_dst     = (float*)alloc((size_t)NN*NH*4);
    int*   esrc      = (int*)  alloc((size_t)NN*MAXDEG*4);   // 2 MB
    int*   cursors   = (int*)  alloc((size_t)NN*4);
    float* beff_part = (float*)alloc((size_t)128*NOUT*4);    // 256 KB
    float* beff      = (float*)alloc((size_t)NOUT*4);
    if ((size_t)(p - (char*)d_ws) > ws_size) return;

    k_phaseA<<<PHA_NB, 256, 0, stream>>>(W_gat, att_src, att_dst, W_lin, b_gat,
                                         Wg, v, WlT, beff_part, cursors);
    k_phaseB<<<PHB_NB, 256, 0, stream>>>(Wg, WlT, eidx, WcT, beff_part, beff,
                                         cursors, esrc, x, v, a_src, a_dst);
    k_agg<<<NN/4, 256, 0, stream>>>(cursors, esrc, a_src, a_dst, x, Ybuf);
    k_gemm64<<<GEMM_NB, 256, 0, stream>>>(Ybuf, WcT, beff, b_lin, out);
}